// Round 10
// baseline (632.631 us; speedup 1.0000x reference)
//
#include <hip/hip_runtime.h>
#include <hip/hip_bf16.h>

#define B_ 2
#define C_ 64
#define H_ 128
#define W_ 128
#define HS 64
#define WS 64
#define L_ 4096
#define S_ 4096
#define K1_ 576    // C*3*3
#define NCOL 1024  // C*4*4
#define SCALE_ 10.0f

typedef __attribute__((ext_vector_type(8))) short bf16x8;
typedef __attribute__((ext_vector_type(4))) float f32x4;

// async global->LDS, 16B per lane (wave-uniform LDS base + lane*16).
__device__ __forceinline__ void async_copy16(const void* gsrc, void* ldst) {
    __builtin_amdgcn_global_load_lds(
        (__attribute__((address_space(1))) const void*)gsrc,
        (__attribute__((address_space(3))) void*)ldst, 16, 0, 0);
}

// LDS chunk swizzle kept for gemm1 only (proven neutral; left to avoid churn there)
__device__ __forceinline__ int sig(int r) { return (r + (r >> 2)) & 3; }

// transposed flat index within a 64x64 grid
__device__ __forceinline__ int TT(int x) { return ((x & 63) << 6) | (x >> 6); }

// generic 3-tap (d2) gather over Y with exact TT boundary semantics
__device__ __forceinline__ float diag3Y(const float* __restrict__ Y, int l, int s) {
    int tl = TT(l), ts = TT(s);
    float acc = 0.f;
#pragma unroll
    for (int d2 = -1; d2 <= 1; ++d2) {
        int p = tl + d2, q = ts + d2;
        if ((unsigned)p < 4096u && (unsigned)q < 4096u)
            acc += Y[((size_t)TT(p) << 12) + TT(q)];
    }
    return acc;
}

// ---------------- K0a: per-pixel channel sum-of-squares of downsampled bg ----------------
__global__ void k_sumsq(const float* __restrict__ bg, float* __restrict__ ssq) {
    int idx = blockIdx.x * 256 + threadIdx.x;  // B*64*64
    if (idx >= B_ * HS * WS) return;
    int pix = idx & 4095, b = idx >> 12;
    int i = pix >> 6, j = pix & 63;
    float ss = 0.f;
    for (int c = 0; c < C_; ++c) {
        float v = bg[((b * C_ + c) * H_ + 2 * i) * W_ + 2 * j];
        ss += v * v;
    }
    ssq[idx] = ss;
}

// ---------------- K0b: per-patch mask flag + 1/denom (3x3 box) ----------------
__global__ void k_patch_stats(const float* __restrict__ mask, const float* __restrict__ ssq,
                              float* __restrict__ denom_inv, float* __restrict__ maskedf) {
    int idx = blockIdx.x * 256 + threadIdx.x;  // B*L
    if (idx >= B_ * L_) return;
    int b = idx >> 12, l = idx & 4095, lh = l >> 6, lw = l & 63;
    float msum = 0.f, ss = 0.f;
    for (int di = -1; di <= 1; ++di)
        for (int dj = -1; dj <= 1; ++dj) {
            int i = lh + di, j = lw + dj;
            if (i >= 0 && i < HS && j >= 0 && j < WS) {
                msum += mask[(b * H_ + 2 * i) * W_ + 2 * j];
                ss += ssq[(b << 12) + (i << 6) + j];
            }
        }
    maskedf[idx] = (msum == 0.0f) ? 1.0f : 0.0f;
    denom_inv[idx] = 1.0f / fmaxf(sqrtf(ss), 0.001f);
}

// ---------------- K0c: fused im2col for bg AND fg (3x3, pad 1, 2x-downsampled) ----------
__global__ void k_im2col2(const float* __restrict__ bgb, const float* __restrict__ fgb,
                          __hip_bfloat16* __restrict__ bhi, __hip_bfloat16* __restrict__ blo,
                          __hip_bfloat16* __restrict__ fhi, __hip_bfloat16* __restrict__ flo) {
    int idx = blockIdx.x * 256 + threadIdx.x;  // 2*L*576
    int which = idx >= L_ * K1_;               // block-uniform (exact division)
    int id = which ? idx - L_ * K1_ : idx;
    const float* src = which ? fgb : bgb;
    __hip_bfloat16* hi = which ? fhi : bhi;
    __hip_bfloat16* lo = which ? flo : blo;
    int k = id % K1_;
    int l = id / K1_;
    int c = k / 9, r = k - 9 * c;
    int r3 = r / 3;
    int di = r3 - 1, dj = r - 3 * r3 - 1;
    int i = (l >> 6) + di, j = (l & 63) + dj;
    float v = 0.f;
    if (i >= 0 && i < HS && j >= 0 && j < WS) v = src[(c * H_ + 2 * i) * W_ + 2 * j];
    __hip_bfloat16 h = __float2bfloat16(v);
    hi[id] = h;
    lo[id] = __float2bfloat16(v - __bfloat162float(h));
}

// ---------------- K1: scores GEMM, split-bf16 MFMA (fp32-equivalent), single batch --------
__global__ __launch_bounds__(256) void k_gemm1_mfma(const __hip_bfloat16* __restrict__ Ahi,
                                                    const __hip_bfloat16* __restrict__ Alo,
                                                    const __hip_bfloat16* __restrict__ Bhi,
                                                    const __hip_bfloat16* __restrict__ Blo,
                                                    const float* __restrict__ dinv,
                                                    float* __restrict__ scores) {
    __shared__ __hip_bfloat16 AsH[128 * 32], AsL[128 * 32], BsH[128 * 32], BsL[128 * 32];
    int t = threadIdx.x, lane = t & 63, w = t >> 6;
    int wm = w & 1, wn = w >> 1;
    int M0 = blockIdx.y * 128, N0 = blockIdx.x * 128;
    int srow = lane >> 2;
    f32x4 acc[4][4] = {};
    for (int k0 = 0; k0 < K1_; k0 += 32) {
#pragma unroll
        for (int q = 0; q < 2; ++q) {
            int r = q * 64 + w * 16;
            int row = r + srow;
            int sch = (((lane & 3) ^ sig(row)) << 3);  // swizzled source chunk
            size_t ga = (size_t)(M0 + row) * K1_ + k0 + sch;
            size_t gb = (size_t)(N0 + row) * K1_ + k0 + sch;
            int lo_ = r * 32;
            async_copy16(Ahi + ga, &AsH[lo_]);
            async_copy16(Alo + ga, &AsL[lo_]);
            async_copy16(Bhi + gb, &BsH[lo_]);
            async_copy16(Blo + gb, &BsL[lo_]);
        }
        __syncthreads();
        int qc = lane >> 4, mr = lane & 15;
        bf16x8 ah[4], al[4], bh[4], bl[4];
#pragma unroll
        for (int i = 0; i < 4; ++i) {
            int rowa = wm * 64 + i * 16 + mr;
            int rowb = wn * 64 + i * 16 + mr;
            int ra = rowa * 32 + ((qc ^ sig(rowa)) << 3);
            int rb = rowb * 32 + ((qc ^ sig(rowb)) << 3);
            ah[i] = *(const bf16x8*)&AsH[ra];
            al[i] = *(const bf16x8*)&AsL[ra];
            bh[i] = *(const bf16x8*)&BsH[rb];
            bl[i] = *(const bf16x8*)&BsL[rb];
        }
#pragma unroll
        for (int mt = 0; mt < 4; ++mt)
#pragma unroll
            for (int nt = 0; nt < 4; ++nt) {
                acc[mt][nt] = __builtin_amdgcn_mfma_f32_16x16x32_bf16(ah[mt], bh[nt], acc[mt][nt], 0, 0, 0);
                acc[mt][nt] = __builtin_amdgcn_mfma_f32_16x16x32_bf16(ah[mt], bl[nt], acc[mt][nt], 0, 0, 0);
                acc[mt][nt] = __builtin_amdgcn_mfma_f32_16x16x32_bf16(al[mt], bh[nt], acc[mt][nt], 0, 0, 0);
            }
        __syncthreads();
    }
    int col = lane & 15, rq = (lane >> 4) * 4;
#pragma unroll
    for (int mt = 0; mt < 4; ++mt)
#pragma unroll
        for (int r = 0; r < 4; ++r) {
            int m = M0 + wm * 64 + mt * 16 + rq + r;
            float dv = dinv[m];
#pragma unroll
            for (int nt = 0; nt < 4; ++nt) {
                int n = N0 + wn * 64 + nt * 16 + col;
                scores[(size_t)m * 4096 + n] = acc[mt][nt][r] * dv;
            }
        }
}

// ---------------- K2a: pass1 — flat diagonal 3-tap: Y[a][c] = sum_d1 scores[a+d1][c+d1] ---
__global__ __launch_bounds__(256) void k_pass1(const float* __restrict__ scores,
                                               float* __restrict__ Y) {
    int gid = blockIdx.x * 256 + threadIdx.x;  // 4096 rows x 1024 f4-cols
    int c4 = gid & 1023, a = gid >> 10;
    int lane = threadIdx.x & 63;
    const float* r0 = scores + ((size_t)a << 12);
    float4 Bv = ((const float4*)r0)[c4];
    float amx = 0.f, amy = 0.f, amz = 0.f, amw = 0.f;
    float cpx = 0.f, cpy = 0.f, cpz = 0.f, cpw = 0.f;
    if (a > 0) {
        const float* rm = r0 - 4096;
        float4 A = ((const float4*)rm)[c4];
        float prev = __shfl_up(A.w, 1);
        if (lane == 0) prev = (c4 > 0) ? rm[4 * c4 - 1] : 0.f;
        amx = prev; amy = A.x; amz = A.y; amw = A.z;
    }
    if (a < 4095) {
        const float* rp = r0 + 4096;
        float4 Cv = ((const float4*)rp)[c4];
        float nxt = __shfl_down(Cv.x, 1);
        if (lane == 63) nxt = (c4 < 1023) ? rp[4 * c4 + 4] : 0.f;
        cpx = Cv.y; cpy = Cv.z; cpz = Cv.w; cpw = nxt;
    }
    float4 o;
    o.x = amx + Bv.x + cpx;
    o.y = amy + Bv.y + cpy;
    o.z = amz + Bv.z + cpz;
    o.w = amw + Bv.w + cpw;
    ((float4*)(Y + ((size_t)a << 12)))[c4] = o;
}

// ---------------- K2b: pass2 — 3-tap (rows +-64) + local-max exp + transpose -> softT -----
__global__ __launch_bounds__(256) void k_soft3(const float* __restrict__ Y,
                                               const float* __restrict__ maskedf,
                                               __hip_bfloat16* __restrict__ softT,
                                               float* __restrict__ pml, float* __restrict__ pz) {
    __shared__ float tile[64][65];
    __shared__ float red[16][64];
    __shared__ float mloc[64];
    int t = threadIdx.x;
    int sx4 = t & 15, lg = t >> 4;
    int bx = blockIdx.x, by = blockIdx.y;
    int s0 = bx * 64, l0 = by * 64;
    bool interior = (bx >= 1) && (bx <= 62) && (by >= 1) && (by <= 62);
    float p0 = -3.0e38f, p1 = -3.0e38f, p2 = -3.0e38f, p3 = -3.0e38f;
    if (interior) {
#pragma unroll
        for (int j = 0; j < 4; ++j) {
            int lloc = lg + 16 * j;
            int l = l0 + lloc;
            float a0 = 0.f, a1 = 0.f, a2 = 0.f, a3 = 0.f;
#pragma unroll
            for (int d2 = -1; d2 <= 1; ++d2) {
                const float* p = Y + ((size_t)(64 * (by + d2) + lloc) << 12) + 64 * (bx + d2) + 4 * sx4;
                float4 v = *(const float4*)p;
                a0 += v.x; a1 += v.y; a2 += v.z; a3 += v.w;
            }
            if (maskedf[l] != 0.f) { a0 = -1000.f; a1 = -1000.f; a2 = -1000.f; a3 = -1000.f; }
            tile[lloc][4 * sx4 + 0] = a0;
            tile[lloc][4 * sx4 + 1] = a1;
            tile[lloc][4 * sx4 + 2] = a2;
            tile[lloc][4 * sx4 + 3] = a3;
            p0 = fmaxf(p0, a0); p1 = fmaxf(p1, a1); p2 = fmaxf(p2, a2); p3 = fmaxf(p3, a3);
        }
    } else {
#pragma unroll
        for (int j = 0; j < 4; ++j) {
            int lloc = lg + 16 * j;
            int l = l0 + lloc;
            bool mk = (maskedf[l] != 0.f);
            float a0 = mk ? -1000.f : diag3Y(Y, l, s0 + 4 * sx4 + 0);
            float a1 = mk ? -1000.f : diag3Y(Y, l, s0 + 4 * sx4 + 1);
            float a2 = mk ? -1000.f : diag3Y(Y, l, s0 + 4 * sx4 + 2);
            float a3 = mk ? -1000.f : diag3Y(Y, l, s0 + 4 * sx4 + 3);
            tile[lloc][4 * sx4 + 0] = a0;
            tile[lloc][4 * sx4 + 1] = a1;
            tile[lloc][4 * sx4 + 2] = a2;
            tile[lloc][4 * sx4 + 3] = a3;
            p0 = fmaxf(p0, a0); p1 = fmaxf(p1, a1); p2 = fmaxf(p2, a2); p3 = fmaxf(p3, a3);
        }
    }
    red[lg][4 * sx4 + 0] = p0;
    red[lg][4 * sx4 + 1] = p1;
    red[lg][4 * sx4 + 2] = p2;
    red[lg][4 * sx4 + 3] = p3;
    __syncthreads();
    if (t < 64) {
        float m = -3.0e38f;
#pragma unroll
        for (int g = 0; g < 16; ++g) m = fmaxf(m, red[g][t]);
        mloc[t] = m;
        pml[(by << 12) + s0 + t] = m;
    }
    __syncthreads();
    float m0 = mloc[4 * sx4 + 0], m1 = mloc[4 * sx4 + 1], m2 = mloc[4 * sx4 + 2], m3 = mloc[4 * sx4 + 3];
    float z0 = 0.f, z1 = 0.f, z2 = 0.f, z3 = 0.f;
#pragma unroll
    for (int j = 0; j < 4; ++j) {
        int lloc = lg + 16 * j;
        float e0 = __expf(SCALE_ * (tile[lloc][4 * sx4 + 0] - m0));
        float e1 = __expf(SCALE_ * (tile[lloc][4 * sx4 + 1] - m1));
        float e2 = __expf(SCALE_ * (tile[lloc][4 * sx4 + 2] - m2));
        float e3 = __expf(SCALE_ * (tile[lloc][4 * sx4 + 3] - m3));
        tile[lloc][4 * sx4 + 0] = e0;
        tile[lloc][4 * sx4 + 1] = e1;
        tile[lloc][4 * sx4 + 2] = e2;
        tile[lloc][4 * sx4 + 3] = e3;
        z0 += e0; z1 += e1; z2 += e2; z3 += e3;
    }
    red[lg][4 * sx4 + 0] = z0;
    red[lg][4 * sx4 + 1] = z1;
    red[lg][4 * sx4 + 2] = z2;
    red[lg][4 * sx4 + 3] = z3;
    __syncthreads();
    if (t < 64) {
        float zz = 0.f;
#pragma unroll
        for (int g = 0; g < 16; ++g) zz += red[g][t];
        pz[(by << 12) + s0 + t] = zz;
    }
    int sxx = t & 63, tg4 = t >> 6;
#pragma unroll
    for (int i = 0; i < 16; ++i) {
        int sloc = tg4 * 16 + i;
        softT[((size_t)(s0 + sloc) << 12) + l0 + sxx] = __float2bfloat16(tile[sxx][sloc]);
    }
}

// ---------------- K3: global fixup: M, fac[c][s]=exp(10(pml-M)), Zinv ----------------
__global__ void k_zfix(const float* __restrict__ pml, const float* __restrict__ pz,
                       float* __restrict__ fac, float* __restrict__ Zinv) {
    int s = blockIdx.x * 256 + threadIdx.x;  // 4096
    float gm = -3.0e38f;
#pragma unroll 4
    for (int c = 0; c < 64; ++c) gm = fmaxf(gm, pml[(c << 12) + s]);
    float gz = 0.f;
#pragma unroll 4
    for (int c = 0; c < 64; ++c) {
        float fc = __expf(SCALE_ * (pml[(c << 12) + s] - gm));
        fac[(c << 12) + s] = fc;
        gz += pz[(c << 12) + s] * fc;
    }
    Zinv[s] = 1.0f / gz;
}

// ---------------- K3b: softT[s][l] *= fac[l>>6][s] (bf16x8 streaming) ----------------
__global__ void k_rescale(__hip_bfloat16* __restrict__ softT, const float* __restrict__ fac) {
    int idx = blockIdx.x * 256 + threadIdx.x;  // 2,097,152 (x8 elements)
    size_t base = (size_t)idx << 3;
    int l = (int)(base & 4095), s = (int)(base >> 12);
    float f = fac[((l >> 6) << 12) + s];
    bf16x8 v = *(const bf16x8*)(softT + base);
    bf16x8 o;
#pragma unroll
    for (int k = 0; k < 8; ++k) {
        unsigned short us = (unsigned short)v[k];
        float x = __uint_as_float((unsigned)us << 16) * f;
        __hip_bfloat16 r = __float2bfloat16(x);
        o[k] = *reinterpret_cast<short*>(&r);
    }
    *(bf16x8*)(softT + base) = o;
}

// ---------------- K5: cols_T[n][l] bf16 (4x4 bg patches, stride 2, pad 1), single batch ---
__global__ void k_colsT(const float* __restrict__ bgb, __hip_bfloat16* __restrict__ colsT) {
    int idx = blockIdx.x * 256 + threadIdx.x;  // NCOL*L, l fastest
    int l = idx & 4095, n = idx >> 12;
    int kj = n & 3, ki = (n >> 2) & 3, c = n >> 4;
    int y = 2 * (l >> 6) + ki - 1, x = 2 * (l & 63) + kj - 1;
    float v = 0.f;
    if (y >= 0 && y < H_ && x >= 0 && x < W_) v = bgb[(c * H_ + y) * W_ + x];
    colsT[idx] = __float2bfloat16(v);
}

// ---------------- K6: deconv GEMM, split-K (z=2) + BK=64, bf16 MFMA, 128x64 tiles ---------
// patchP[z][m][n] = Zinv[m] * sum_{k in half z} softT[m][k]*colsT[n][k]
__global__ __launch_bounds__(256) void k_gemm2_mfma(const __hip_bfloat16* __restrict__ softT,
                                                    const __hip_bfloat16* __restrict__ colsT,
                                                    const float* __restrict__ Zinv,
                                                    float* __restrict__ patchP) {
    __shared__ __hip_bfloat16 As[128 * 64], Bs[64 * 64];
    int t = threadIdx.x, lane = t & 63, w = t >> 6;
    int wm = w & 1, wn = w >> 1;
    int M0 = blockIdx.y * 128, N0 = blockIdx.x * 64;
    int kbase = blockIdx.z * 2048;
    f32x4 acc[4][2] = {};
    for (int k0 = kbase; k0 < kbase + 2048; k0 += 64) {
        // stage A: 128 rows x 64 bf16 = 1024 chunks of 16B; thread t does 4
#pragma unroll
        for (int rp = 0; rp < 4; ++rp) {
            int chunk = rp * 256 + t;
            int row = chunk >> 3, c8 = (chunk & 7) * 8;
            async_copy16(softT + ((size_t)(M0 + row) << 12) + k0 + c8, &As[chunk * 8]);
        }
        // stage B: 64 rows x 64 bf16 = 512 chunks; thread t does 2
#pragma unroll
        for (int rp = 0; rp < 2; ++rp) {
            int chunk = rp * 256 + t;
            int row = chunk >> 3, c8 = (chunk & 7) * 8;
            async_copy16(colsT + ((size_t)(N0 + row) << 12) + k0 + c8, &Bs[chunk * 8]);
        }
        __syncthreads();
        int qc = lane >> 4, mr = lane & 15;
#pragma unroll
        for (int kk = 0; kk < 2; ++kk) {
            bf16x8 af[4], bfr[2];
#pragma unroll
            for (int i = 0; i < 4; ++i) {
                int rowa = wm * 64 + i * 16 + mr;
                af[i] = *(const bf16x8*)&As[rowa * 64 + (kk * 4 + qc) * 8];
            }
#pragma unroll
            for (int j = 0; j < 2; ++j) {
                int rowb = wn * 32 + j * 16 + mr;
                bfr[j] = *(const bf16x8*)&Bs[rowb * 64 + (kk * 4 + qc) * 8];
            }
#pragma unroll
            for (int mt = 0; mt < 4; ++mt)
#pragma unroll
                for (int nt = 0; nt < 2; ++nt)
                    acc[mt][nt] = __builtin_amdgcn_mfma_f32_16x16x32_bf16(af[mt], bfr[nt], acc[mt][nt], 0, 0, 0);
        }
        __syncthreads();
    }
    float* P = patchP + ((size_t)blockIdx.z << 22);
    int col = lane & 15, rq = (lane >> 4) * 4;
#pragma unroll
    for (int mt = 0; mt < 4; ++mt)
#pragma unroll
        for (int r = 0; r < 4; ++r) {
            int m = M0 + wm * 64 + mt * 16 + rq + r;
            float zi = Zinv[m];
#pragma unroll
            for (int nt = 0; nt < 2; ++nt) {
                int n = N0 + wn * 32 + nt * 16 + col;
                P[(size_t)m * 1024 + n] = acc[mt][nt][r] * zi;
            }
        }
}

// ---------------- K7: overlap-add gather over both K-partials, single batch ---------------
__global__ void k_col2im(const float* __restrict__ patchP, float* __restrict__ outb) {
    int idx = blockIdx.x * 256 + threadIdx.x;  // C*H*W
    if (idx >= C_ * H_ * W_) return;
    int x = idx & 127, y = (idx >> 7) & 127, c = idx >> 14;
    const float* P0 = patchP;
    const float* P1 = patchP + (1u << 22);
    float acc = 0.f;
    int ki0 = (y + 1) & 1, kj0 = (x + 1) & 1;
#pragma unroll
    for (int ki = ki0; ki < 4; ki += 2) {
        int i = (y + 1 - ki) >> 1;
        if (i < 0 || i >= HS) continue;
#pragma unroll
        for (int kj = kj0; kj < 4; kj += 2) {
            int j = (x + 1 - kj) >> 1;
            if (j < 0 || j >= WS) continue;
            size_t off = ((size_t)(i * 64 + j) << 10) + c * 16 + ki * 4 + kj;
            acc += P0[off] + P1[off];
        }
    }
    outb[idx] = acc;
}

extern "C" void kernel_launch(void* const* d_in, const int* in_sizes, int n_in,
                              void* d_out, int out_size, void* d_ws, size_t ws_size,
                              hipStream_t stream) {
    (void)in_sizes; (void)n_in; (void)out_size; (void)ws_size;
    const float* fg = (const float*)d_in[0];
    const float* bg = (const float*)d_in[1];
    const float* mask = (const float*)d_in[2];
    float* out = (float*)d_out;

    // ---- workspace (float offsets), total ~44.86M f = 171.1 MiB ----
    float* ws = (float*)d_ws;
    float* scores = ws;                                          // 16,777,216 f
    float* patchP = ws;                                          // alias: 2 x 4,194,304 f (scores dead after pass1)
    float* Y = ws + 16777216;                                    // 16,777,216 f
    __hip_bfloat16* bgcol_hi = (__hip_bfloat16*)(ws + 16777216); // im2col buffers alias Y region
    __hip_bfloat16* bgcol_lo = (__hip_bfloat16*)(ws + 17956864);
    __hip_bfloat16* fgcol_hi = (__hip_bfloat16*)(ws + 19136512);
    __hip_bfloat16* fgcol_lo = (__hip_bfloat16*)(ws + 20316160);
    __hip_bfloat16* softT = (__hip_bfloat16*)(ws + 33554432);    // 16,777,216 bf16
    __hip_bfloat16* colsT = (__hip_bfloat16*)(ws + 41943040);    // 4,194,304 bf16
    float* pml = ws + 44040192;        // 262,144 (64 x 4096)
    float* pz = ws + 44302336;         // 262,144
    float* fac = ws + 44564480;        // 262,144
    float* denom_inv = ws + 44826624;  // 8,192 (B*L)
    float* maskedf = ws + 44834816;    // 8,192 (B*L)
    float* ssq = ws + 44843008;        // 8,192
    float* Zinv = ws + 44851200;       // 4,096

    k_sumsq<<<(B_ * HS * WS) / 256, 256, 0, stream>>>(bg, ssq);
    k_patch_stats<<<(B_ * L_) / 256, 256, 0, stream>>>(mask, ssq, denom_inv, maskedf);

    for (int b = 0; b < B_; ++b) {
        const float* bgb = bg + (size_t)b * C_ * H_ * W_;
        const float* fgb = fg + (size_t)b * C_ * H_ * W_;

        k_im2col2<<<(2 * L_ * K1_) / 256, 256, 0, stream>>>(bgb, fgb, bgcol_hi, bgcol_lo,
                                                            fgcol_hi, fgcol_lo);
        k_colsT<<<(NCOL * L_) / 256, 256, 0, stream>>>(bgb, colsT);

        dim3 g1(32, 32);
        k_gemm1_mfma<<<g1, 256, 0, stream>>>(bgcol_hi, bgcol_lo, fgcol_hi, fgcol_lo,
                                             denom_inv + b * L_, scores);

        k_pass1<<<(L_ * S_ / 4) / 256, 256, 0, stream>>>(scores, Y);

        dim3 g4(64, 64);
        k_soft3<<<g4, 256, 0, stream>>>(Y, maskedf + b * L_, softT, pml, pz);
        k_zfix<<<16, 256, 0, stream>>>(pml, pz, fac, Zinv);
        k_rescale<<<8192, 256, 0, stream>>>(softT, fac);

        dim3 g5(16, 32, 2);
        k_gemm2_mfma<<<g5, 256, 0, stream>>>(softT, colsT, Zinv, patchP);
        k_col2im<<<(C_ * H_ * W_) / 256, 256, 0, stream>>>(patchP, out + (size_t)b * C_ * H_ * W_);
    }
}

// Round 11
// 594.265 us; speedup vs baseline: 1.0646x; 1.0646x over previous
//
#include <hip/hip_runtime.h>
#include <hip/hip_bf16.h>

#define B_ 2
#define C_ 64
#define H_ 128
#define W_ 128
#define HS 64
#define WS 64
#define L_ 4096
#define S_ 4096
#define K1_ 576    // C*3*3
#define NCOL 1024  // C*4*4
#define SCALE_ 10.0f

typedef __attribute__((ext_vector_type(8))) short bf16x8;
typedef __attribute__((ext_vector_type(4))) float f32x4;

// async global->LDS, 16B per lane (wave-uniform LDS base + lane*16).
__device__ __forceinline__ void async_copy16(const void* gsrc, void* ldst) {
    __builtin_amdgcn_global_load_lds(
        (__attribute__((address_space(1))) const void*)gsrc,
        (__attribute__((address_space(3))) void*)ldst, 16, 0, 0);
}

// transposed flat index within a 64x64 grid
__device__ __forceinline__ int TT(int x) { return ((x & 63) << 6) | (x >> 6); }

// generic 3-tap (d2) gather over Y with exact TT boundary semantics
__device__ __forceinline__ float diag3Y(const float* __restrict__ Y, int l, int s) {
    int tl = TT(l), ts = TT(s);
    float acc = 0.f;
#pragma unroll
    for (int d2 = -1; d2 <= 1; ++d2) {
        int p = tl + d2, q = ts + d2;
        if ((unsigned)p < 4096u && (unsigned)q < 4096u)
            acc += Y[((size_t)TT(p) << 12) + TT(q)];
    }
    return acc;
}

// ---------------- K0a: per-pixel channel sum-of-squares of downsampled bg ----------------
__global__ void k_sumsq(const float* __restrict__ bg, float* __restrict__ ssq) {
    int idx = blockIdx.x * 256 + threadIdx.x;  // B*64*64
    if (idx >= B_ * HS * WS) return;
    int pix = idx & 4095, b = idx >> 12;
    int i = pix >> 6, j = pix & 63;
    float ss = 0.f;
    for (int c = 0; c < C_; ++c) {
        float v = bg[((b * C_ + c) * H_ + 2 * i) * W_ + 2 * j];
        ss += v * v;
    }
    ssq[idx] = ss;
}

// ---------------- K0b: per-patch mask flag + 1/denom (3x3 box) ----------------
__global__ void k_patch_stats(const float* __restrict__ mask, const float* __restrict__ ssq,
                              float* __restrict__ denom_inv, float* __restrict__ maskedf) {
    int idx = blockIdx.x * 256 + threadIdx.x;  // B*L
    if (idx >= B_ * L_) return;
    int b = idx >> 12, l = idx & 4095, lh = l >> 6, lw = l & 63;
    float msum = 0.f, ss = 0.f;
    for (int di = -1; di <= 1; ++di)
        for (int dj = -1; dj <= 1; ++dj) {
            int i = lh + di, j = lw + dj;
            if (i >= 0 && i < HS && j >= 0 && j < WS) {
                msum += mask[(b * H_ + 2 * i) * W_ + 2 * j];
                ss += ssq[(b << 12) + (i << 6) + j];
            }
        }
    maskedf[idx] = (msum == 0.0f) ? 1.0f : 0.0f;
    denom_inv[idx] = 1.0f / fmaxf(sqrtf(ss), 0.001f);
}

// ---------------- K0c: fused im2col for bg AND fg (3x3, pad 1, 2x-downsampled) ----------
__global__ void k_im2col2(const float* __restrict__ bgb, const float* __restrict__ fgb,
                          __hip_bfloat16* __restrict__ bhi, __hip_bfloat16* __restrict__ blo,
                          __hip_bfloat16* __restrict__ fhi, __hip_bfloat16* __restrict__ flo) {
    int idx = blockIdx.x * 256 + threadIdx.x;  // 2*L*576
    int which = idx >= L_ * K1_;               // block-uniform (exact division)
    int id = which ? idx - L_ * K1_ : idx;
    const float* src = which ? fgb : bgb;
    __hip_bfloat16* hi = which ? fhi : bhi;
    __hip_bfloat16* lo = which ? flo : blo;
    int k = id % K1_;
    int l = id / K1_;
    int c = k / 9, r = k - 9 * c;
    int r3 = r / 3;
    int di = r3 - 1, dj = r - 3 * r3 - 1;
    int i = (l >> 6) + di, j = (l & 63) + dj;
    float v = 0.f;
    if (i >= 0 && i < HS && j >= 0 && j < WS) v = src[(c * H_ + 2 * i) * W_ + 2 * j];
    __hip_bfloat16 h = __float2bfloat16(v);
    hi[id] = h;
    lo[id] = __float2bfloat16(v - __bfloat162float(h));
}

// ---------------- K1: scores GEMM, split-bf16 MFMA, XCD-swizzled block ids ---------------
// Blocks sharing an A-panel (same y') are given flat ids congruent mod 8 so the
// round-robin dispatch co-locates them on one XCD (shared L2 copy of the panel).
__global__ __launch_bounds__(256) void k_gemm1_mfma(const __hip_bfloat16* __restrict__ Ahi,
                                                    const __hip_bfloat16* __restrict__ Alo,
                                                    const __hip_bfloat16* __restrict__ Bhi,
                                                    const __hip_bfloat16* __restrict__ Blo,
                                                    const float* __restrict__ dinv,
                                                    float* __restrict__ scores) {
    __shared__ __hip_bfloat16 AsH[128 * 32], AsL[128 * 32], BsH[128 * 32], BsL[128 * 32];
    int t = threadIdx.x, lane = t & 63, w = t >> 6;
    int wm = w & 1, wn = w >> 1;
    int flat = blockIdx.x + (blockIdx.y << 5);  // grid (32,32)
    int xp = (flat >> 3) & 31;
    int yp = (flat & 7) | (((flat >> 8) & 3) << 3);
    int M0 = yp * 128, N0 = xp * 128;
    int srow = lane >> 2, schunk = (lane & 3) * 8;
    f32x4 acc[4][4] = {};
    for (int k0 = 0; k0 < K1_; k0 += 32) {
#pragma unroll
        for (int q = 0; q < 2; ++q) {
            int r = q * 64 + w * 16;
            int row = r + srow;
            size_t ga = (size_t)(M0 + row) * K1_ + k0 + schunk;
            size_t gb = (size_t)(N0 + row) * K1_ + k0 + schunk;
            int lo_ = r * 32;
            async_copy16(Ahi + ga, &AsH[lo_]);
            async_copy16(Alo + ga, &AsL[lo_]);
            async_copy16(Bhi + gb, &BsH[lo_]);
            async_copy16(Blo + gb, &BsL[lo_]);
        }
        __syncthreads();
        int q8 = (lane >> 4) * 8, mr = lane & 15;
        bf16x8 ah[4], al[4], bh[4], bl[4];
#pragma unroll
        for (int i = 0; i < 4; ++i) {
            int ra = (wm * 64 + i * 16 + mr) * 32 + q8;
            int rb = (wn * 64 + i * 16 + mr) * 32 + q8;
            ah[i] = *(const bf16x8*)&AsH[ra];
            al[i] = *(const bf16x8*)&AsL[ra];
            bh[i] = *(const bf16x8*)&BsH[rb];
            bl[i] = *(const bf16x8*)&BsL[rb];
        }
#pragma unroll
        for (int mt = 0; mt < 4; ++mt)
#pragma unroll
            for (int nt = 0; nt < 4; ++nt) {
                acc[mt][nt] = __builtin_amdgcn_mfma_f32_16x16x32_bf16(ah[mt], bh[nt], acc[mt][nt], 0, 0, 0);
                acc[mt][nt] = __builtin_amdgcn_mfma_f32_16x16x32_bf16(ah[mt], bl[nt], acc[mt][nt], 0, 0, 0);
                acc[mt][nt] = __builtin_amdgcn_mfma_f32_16x16x32_bf16(al[mt], bh[nt], acc[mt][nt], 0, 0, 0);
            }
        __syncthreads();
    }
    int col = lane & 15, rq = (lane >> 4) * 4;
#pragma unroll
    for (int mt = 0; mt < 4; ++mt)
#pragma unroll
        for (int r = 0; r < 4; ++r) {
            int m = M0 + wm * 64 + mt * 16 + rq + r;
            float dv = dinv[m];
#pragma unroll
            for (int nt = 0; nt < 4; ++nt) {
                int n = N0 + wn * 64 + nt * 16 + col;
                scores[(size_t)m * 4096 + n] = acc[mt][nt][r] * dv;
            }
        }
}

// ---------------- K2a: pass1 — flat diagonal 3-tap: Y[a][c] = sum_d1 scores[a+d1][c+d1] ---
__global__ __launch_bounds__(256) void k_pass1(const float* __restrict__ scores,
                                               float* __restrict__ Y) {
    int gid = blockIdx.x * 256 + threadIdx.x;  // 4096 rows x 1024 f4-cols
    int c4 = gid & 1023, a = gid >> 10;
    int lane = threadIdx.x & 63;
    const float* r0 = scores + ((size_t)a << 12);
    float4 Bv = ((const float4*)r0)[c4];
    float amx = 0.f, amy = 0.f, amz = 0.f, amw = 0.f;
    float cpx = 0.f, cpy = 0.f, cpz = 0.f, cpw = 0.f;
    if (a > 0) {
        const float* rm = r0 - 4096;
        float4 A = ((const float4*)rm)[c4];
        float prev = __shfl_up(A.w, 1);
        if (lane == 0) prev = (c4 > 0) ? rm[4 * c4 - 1] : 0.f;
        amx = prev; amy = A.x; amz = A.y; amw = A.z;
    }
    if (a < 4095) {
        const float* rp = r0 + 4096;
        float4 Cv = ((const float4*)rp)[c4];
        float nxt = __shfl_down(Cv.x, 1);
        if (lane == 63) nxt = (c4 < 1023) ? rp[4 * c4 + 4] : 0.f;
        cpx = Cv.y; cpy = Cv.z; cpz = Cv.w; cpw = nxt;
    }
    float4 o;
    o.x = amx + Bv.x + cpx;
    o.y = amy + Bv.y + cpy;
    o.z = amz + Bv.z + cpz;
    o.w = amw + Bv.w + cpw;
    ((float4*)(Y + ((size_t)a << 12)))[c4] = o;
}

// ---------------- K2b: pass2 — 3-tap (rows +-64) + local-max exp + transpose -> softT -----
__global__ __launch_bounds__(256) void k_soft3(const float* __restrict__ Y,
                                               const float* __restrict__ maskedf,
                                               __hip_bfloat16* __restrict__ softT,
                                               float* __restrict__ pml, float* __restrict__ pz) {
    __shared__ float tile[64][65];
    __shared__ float red[16][64];
    __shared__ float mloc[64];
    int t = threadIdx.x;
    int sx4 = t & 15, lg = t >> 4;
    int bx = blockIdx.x, by = blockIdx.y;
    int s0 = bx * 64, l0 = by * 64;
    bool interior = (bx >= 1) && (bx <= 62) && (by >= 1) && (by <= 62);
    float p0 = -3.0e38f, p1 = -3.0e38f, p2 = -3.0e38f, p3 = -3.0e38f;
    if (interior) {
#pragma unroll
        for (int j = 0; j < 4; ++j) {
            int lloc = lg + 16 * j;
            int l = l0 + lloc;
            float a0 = 0.f, a1 = 0.f, a2 = 0.f, a3 = 0.f;
#pragma unroll
            for (int d2 = -1; d2 <= 1; ++d2) {
                const float* p = Y + ((size_t)(64 * (by + d2) + lloc) << 12) + 64 * (bx + d2) + 4 * sx4;
                float4 v = *(const float4*)p;
                a0 += v.x; a1 += v.y; a2 += v.z; a3 += v.w;
            }
            if (maskedf[l] != 0.f) { a0 = -1000.f; a1 = -1000.f; a2 = -1000.f; a3 = -1000.f; }
            tile[lloc][4 * sx4 + 0] = a0;
            tile[lloc][4 * sx4 + 1] = a1;
            tile[lloc][4 * sx4 + 2] = a2;
            tile[lloc][4 * sx4 + 3] = a3;
            p0 = fmaxf(p0, a0); p1 = fmaxf(p1, a1); p2 = fmaxf(p2, a2); p3 = fmaxf(p3, a3);
        }
    } else {
#pragma unroll
        for (int j = 0; j < 4; ++j) {
            int lloc = lg + 16 * j;
            int l = l0 + lloc;
            bool mk = (maskedf[l] != 0.f);
            float a0 = mk ? -1000.f : diag3Y(Y, l, s0 + 4 * sx4 + 0);
            float a1 = mk ? -1000.f : diag3Y(Y, l, s0 + 4 * sx4 + 1);
            float a2 = mk ? -1000.f : diag3Y(Y, l, s0 + 4 * sx4 + 2);
            float a3 = mk ? -1000.f : diag3Y(Y, l, s0 + 4 * sx4 + 3);
            tile[lloc][4 * sx4 + 0] = a0;
            tile[lloc][4 * sx4 + 1] = a1;
            tile[lloc][4 * sx4 + 2] = a2;
            tile[lloc][4 * sx4 + 3] = a3;
            p0 = fmaxf(p0, a0); p1 = fmaxf(p1, a1); p2 = fmaxf(p2, a2); p3 = fmaxf(p3, a3);
        }
    }
    red[lg][4 * sx4 + 0] = p0;
    red[lg][4 * sx4 + 1] = p1;
    red[lg][4 * sx4 + 2] = p2;
    red[lg][4 * sx4 + 3] = p3;
    __syncthreads();
    if (t < 64) {
        float m = -3.0e38f;
#pragma unroll
        for (int g = 0; g < 16; ++g) m = fmaxf(m, red[g][t]);
        mloc[t] = m;
        pml[(by << 12) + s0 + t] = m;
    }
    __syncthreads();
    float m0 = mloc[4 * sx4 + 0], m1 = mloc[4 * sx4 + 1], m2 = mloc[4 * sx4 + 2], m3 = mloc[4 * sx4 + 3];
    float z0 = 0.f, z1 = 0.f, z2 = 0.f, z3 = 0.f;
#pragma unroll
    for (int j = 0; j < 4; ++j) {
        int lloc = lg + 16 * j;
        float e0 = __expf(SCALE_ * (tile[lloc][4 * sx4 + 0] - m0));
        float e1 = __expf(SCALE_ * (tile[lloc][4 * sx4 + 1] - m1));
        float e2 = __expf(SCALE_ * (tile[lloc][4 * sx4 + 2] - m2));
        float e3 = __expf(SCALE_ * (tile[lloc][4 * sx4 + 3] - m3));
        tile[lloc][4 * sx4 + 0] = e0;
        tile[lloc][4 * sx4 + 1] = e1;
        tile[lloc][4 * sx4 + 2] = e2;
        tile[lloc][4 * sx4 + 3] = e3;
        z0 += e0; z1 += e1; z2 += e2; z3 += e3;
    }
    red[lg][4 * sx4 + 0] = z0;
    red[lg][4 * sx4 + 1] = z1;
    red[lg][4 * sx4 + 2] = z2;
    red[lg][4 * sx4 + 3] = z3;
    __syncthreads();
    if (t < 64) {
        float zz = 0.f;
#pragma unroll
        for (int g = 0; g < 16; ++g) zz += red[g][t];
        pz[(by << 12) + s0 + t] = zz;
    }
    int sxx = t & 63, tg4 = t >> 6;
#pragma unroll
    for (int i = 0; i < 16; ++i) {
        int sloc = tg4 * 16 + i;
        softT[((size_t)(s0 + sloc) << 12) + l0 + sxx] = __float2bfloat16(tile[sxx][sloc]);
    }
}

// ---------------- K3: fused zfix+rescale: block per s-row --------------------------------
// Wave 0 reduces 64 (pml,pz) partials -> fac[c]*Zinv in LDS; whole block rescales its row.
__global__ __launch_bounds__(256) void k_zr(const float* __restrict__ pml,
                                            const float* __restrict__ pz,
                                            __hip_bfloat16* __restrict__ softT) {
    __shared__ float facs[64];
    int t = threadIdx.x;
    int s = blockIdx.x;
    if (t < 64) {
        float pmv = pml[(t << 12) + s];
        float m = pmv;
#pragma unroll
        for (int off = 1; off < 64; off <<= 1) m = fmaxf(m, __shfl_xor(m, off));
        float fc = __expf(SCALE_ * (pmv - m));
        float g = pz[(t << 12) + s] * fc;
#pragma unroll
        for (int off = 1; off < 64; off <<= 1) g += __shfl_xor(g, off);
        facs[t] = fc * (1.0f / g);
    }
    __syncthreads();
    size_t rowbase = (size_t)s << 12;
#pragma unroll
    for (int p = 0; p < 2; ++p) {
        int chunk = t + p * 256;
        float f = facs[chunk >> 3];
        bf16x8 v = *(const bf16x8*)(softT + rowbase + chunk * 8);
        bf16x8 o;
#pragma unroll
        for (int k = 0; k < 8; ++k) {
            unsigned short us = (unsigned short)v[k];
            float x = __uint_as_float((unsigned)us << 16) * f;
            __hip_bfloat16 r = __float2bfloat16(x);
            o[k] = *reinterpret_cast<short*>(&r);
        }
        *(bf16x8*)(softT + rowbase + chunk * 8) = o;
    }
}

// ---------------- K5: cols_T[n][l] bf16 (4x4 bg patches, stride 2, pad 1), single batch ---
__global__ void k_colsT(const float* __restrict__ bgb, __hip_bfloat16* __restrict__ colsT) {
    int idx = blockIdx.x * 256 + threadIdx.x;  // NCOL*L, l fastest
    int l = idx & 4095, n = idx >> 12;
    int kj = n & 3, ki = (n >> 2) & 3, c = n >> 4;
    int y = 2 * (l >> 6) + ki - 1, x = 2 * (l & 63) + kj - 1;
    float v = 0.f;
    if (y >= 0 && y < H_ && x >= 0 && x < W_) v = bgb[(c * H_ + y) * W_ + x];
    colsT[idx] = __float2bfloat16(v);
}

// ---------------- K6: deconv GEMM, split-K z=2, BK=64, XCD-swizzled block ids -------------
// softT already carries fac*Zinv, so D = plain accumulate.
__global__ __launch_bounds__(256) void k_gemm2_mfma(const __hip_bfloat16* __restrict__ softT,
                                                    const __hip_bfloat16* __restrict__ colsT,
                                                    float* __restrict__ patchP) {
    __shared__ __hip_bfloat16 As[128 * 64], Bs[64 * 64];
    int t = threadIdx.x, lane = t & 63, w = t >> 6;
    int wm = w & 1, wn = w >> 1;
    int flat = blockIdx.x + (blockIdx.y << 4) + (blockIdx.z << 9);  // grid (16,32,2)
    int xp = (flat >> 3) & 15;
    int yp = (flat & 7) | (((flat >> 7) & 3) << 3);
    int zp = flat >> 9;
    int M0 = yp * 128, N0 = xp * 64;
    int kbase = zp * 2048;
    f32x4 acc[4][2] = {};
    for (int k0 = kbase; k0 < kbase + 2048; k0 += 64) {
#pragma unroll
        for (int rp = 0; rp < 4; ++rp) {
            int chunk = rp * 256 + t;
            int row = chunk >> 3, c8 = (chunk & 7) * 8;
            async_copy16(softT + ((size_t)(M0 + row) << 12) + k0 + c8, &As[chunk * 8]);
        }
#pragma unroll
        for (int rp = 0; rp < 2; ++rp) {
            int chunk = rp * 256 + t;
            int row = chunk >> 3, c8 = (chunk & 7) * 8;
            async_copy16(colsT + ((size_t)(N0 + row) << 12) + k0 + c8, &Bs[chunk * 8]);
        }
        __syncthreads();
        int qc = lane >> 4, mr = lane & 15;
#pragma unroll
        for (int kk = 0; kk < 2; ++kk) {
            bf16x8 af[4], bfr[2];
#pragma unroll
            for (int i = 0; i < 4; ++i) {
                int rowa = wm * 64 + i * 16 + mr;
                af[i] = *(const bf16x8*)&As[rowa * 64 + (kk * 4 + qc) * 8];
            }
#pragma unroll
            for (int j = 0; j < 2; ++j) {
                int rowb = wn * 32 + j * 16 + mr;
                bfr[j] = *(const bf16x8*)&Bs[rowb * 64 + (kk * 4 + qc) * 8];
            }
#pragma unroll
            for (int mt = 0; mt < 4; ++mt)
#pragma unroll
                for (int nt = 0; nt < 2; ++nt)
                    acc[mt][nt] = __builtin_amdgcn_mfma_f32_16x16x32_bf16(af[mt], bfr[nt], acc[mt][nt], 0, 0, 0);
        }
        __syncthreads();
    }
    float* P = patchP + ((size_t)zp << 22);
    int col = lane & 15, rq = (lane >> 4) * 4;
#pragma unroll
    for (int mt = 0; mt < 4; ++mt)
#pragma unroll
        for (int r = 0; r < 4; ++r) {
            int m = M0 + wm * 64 + mt * 16 + rq + r;
#pragma unroll
            for (int nt = 0; nt < 2; ++nt) {
                int n = N0 + wn * 32 + nt * 16 + col;
                P[(size_t)m * 1024 + n] = acc[mt][nt][r];
            }
        }
}

// ---------------- K7: overlap-add gather over both K-partials, single batch ---------------
__global__ void k_col2im(const float* __restrict__ patchP, float* __restrict__ outb) {
    int idx = blockIdx.x * 256 + threadIdx.x;  // C*H*W
    if (idx >= C_ * H_ * W_) return;
    int x = idx & 127, y = (idx >> 7) & 127, c = idx >> 14;
    const float* P0 = patchP;
    const float* P1 = patchP + (1u << 22);
    float acc = 0.f;
    int ki0 = (y + 1) & 1, kj0 = (x + 1) & 1;
#pragma unroll
    for (int ki = ki0; ki < 4; ki += 2) {
        int i = (y + 1 - ki) >> 1;
        if (i < 0 || i >= HS) continue;
#pragma unroll
        for (int kj = kj0; kj < 4; kj += 2) {
            int j = (x + 1 - kj) >> 1;
            if (j < 0 || j >= WS) continue;
            size_t off = ((size_t)(i * 64 + j) << 10) + c * 16 + ki * 4 + kj;
            acc += P0[off] + P1[off];
        }
    }
    outb[idx] = acc;
}

extern "C" void kernel_launch(void* const* d_in, const int* in_sizes, int n_in,
                              void* d_out, int out_size, void* d_ws, size_t ws_size,
                              hipStream_t stream) {
    (void)in_sizes; (void)n_in; (void)out_size; (void)ws_size;
    const float* fg = (const float*)d_in[0];
    const float* bg = (const float*)d_in[1];
    const float* mask = (const float*)d_in[2];
    float* out = (float*)d_out;

    // ---- workspace (float offsets), total ~44.86M f = 171.1 MiB ----
    float* ws = (float*)d_ws;
    float* scores = ws;                                          // 16,777,216 f
    float* patchP = ws;                                          // alias: 2 x 4,194,304 f (scores dead after pass1)
    float* Y = ws + 16777216;                                    // 16,777,216 f
    __hip_bfloat16* bgcol_hi = (__hip_bfloat16*)(ws + 16777216); // im2col buffers alias Y region
    __hip_bfloat16* bgcol_lo = (__hip_bfloat16*)(ws + 17956864);
    __hip_bfloat16* fgcol_hi = (__hip_bfloat16*)(ws + 19136512);
    __hip_bfloat16* fgcol_lo = (__hip_bfloat16*)(ws + 20316160);
    __hip_bfloat16* softT = (__hip_bfloat16*)(ws + 33554432);    // 16,777,216 bf16
    __hip_bfloat16* colsT = (__hip_bfloat16*)(ws + 41943040);    // 4,194,304 bf16
    float* pml = ws + 44040192;        // 262,144 (64 x 4096)
    float* pz = ws + 44302336;         // 262,144
    float* denom_inv = ws + 44826624;  // 8,192 (B*L)
    float* maskedf = ws + 44834816;    // 8,192 (B*L)
    float* ssq = ws + 44843008;        // 8,192

    k_sumsq<<<(B_ * HS * WS) / 256, 256, 0, stream>>>(bg, ssq);
    k_patch_stats<<<(B_ * L_) / 256, 256, 0, stream>>>(mask, ssq, denom_inv, maskedf);

    for (int b = 0; b < B_; ++b) {
        const float* bgb = bg + (size_t)b * C_ * H_ * W_;
        const float* fgb = fg + (size_t)b * C_ * H_ * W_;

        k_im2col2<<<(2 * L_ * K1_) / 256, 256, 0, stream>>>(bgb, fgb, bgcol_hi, bgcol_lo,
                                                            fgcol_hi, fgcol_lo);
        k_colsT<<<(NCOL * L_) / 256, 256, 0, stream>>>(bgb, colsT);

        dim3 g1(32, 32);
        k_gemm1_mfma<<<g1, 256, 0, stream>>>(bgcol_hi, bgcol_lo, fgcol_hi, fgcol_lo,
                                             denom_inv + b * L_, scores);

        k_pass1<<<(L_ * S_ / 4) / 256, 256, 0, stream>>>(scores, Y);

        dim3 g4(64, 64);
        k_soft3<<<g4, 256, 0, stream>>>(Y, maskedf + b * L_, softT, pml, pz);
        k_zr<<<4096, 256, 0, stream>>>(pml, pz, softT);

        dim3 g5(16, 32, 2);
        k_gemm2_mfma<<<g5, 256, 0, stream>>>(softT, colsT, patchP);
        k_col2im<<<(C_ * H_ * W_) / 256, 256, 0, stream>>>(patchP, out + (size_t)b * C_ * H_ * W_);
    }
}

// Round 12
// 579.007 us; speedup vs baseline: 1.0926x; 1.0264x over previous
//
#include <hip/hip_runtime.h>
#include <hip/hip_bf16.h>

#define B_ 2
#define C_ 64
#define H_ 128
#define W_ 128
#define HS 64
#define WS 64
#define L_ 4096
#define S_ 4096
#define K1_ 576    // C*3*3
#define NCOL 1024  // C*4*4
#define SCALE_ 10.0f

typedef __attribute__((ext_vector_type(8))) short bf16x8;
typedef __attribute__((ext_vector_type(4))) float f32x4;

// async global->LDS, 16B per lane (wave-uniform LDS base + lane*16).
__device__ __forceinline__ void async_copy16(const void* gsrc, void* ldst) {
    __builtin_amdgcn_global_load_lds(
        (__attribute__((address_space(1))) const void*)gsrc,
        (__attribute__((address_space(3))) void*)ldst, 16, 0, 0);
}

// transposed flat index within a 64x64 grid
__device__ __forceinline__ int TT(int x) { return ((x & 63) << 6) | (x >> 6); }

// generic 3-tap (d2) gather over Y with exact TT boundary semantics
__device__ __forceinline__ float diag3Y(const float* __restrict__ Y, int l, int s) {
    int tl = TT(l), ts = TT(s);
    float acc = 0.f;
#pragma unroll
    for (int d2 = -1; d2 <= 1; ++d2) {
        int p = tl + d2, q = ts + d2;
        if ((unsigned)p < 4096u && (unsigned)q < 4096u)
            acc += Y[((size_t)TT(p) << 12) + TT(q)];
    }
    return acc;
}

// ---------------- K0a: per-pixel channel sum-of-squares of downsampled bg ----------------
__global__ void k_sumsq(const float* __restrict__ bg, float* __restrict__ ssq) {
    int idx = blockIdx.x * 256 + threadIdx.x;  // B*64*64
    if (idx >= B_ * HS * WS) return;
    int pix = idx & 4095, b = idx >> 12;
    int i = pix >> 6, j = pix & 63;
    float ss = 0.f;
    for (int c = 0; c < C_; ++c) {
        float v = bg[((b * C_ + c) * H_ + 2 * i) * W_ + 2 * j];
        ss += v * v;
    }
    ssq[idx] = ss;
}

// ---------------- K0b: per-patch mask flag + 1/denom (3x3 box) ----------------
__global__ void k_patch_stats(const float* __restrict__ mask, const float* __restrict__ ssq,
                              float* __restrict__ denom_inv, float* __restrict__ maskedf) {
    int idx = blockIdx.x * 256 + threadIdx.x;  // B*L
    if (idx >= B_ * L_) return;
    int b = idx >> 12, l = idx & 4095, lh = l >> 6, lw = l & 63;
    float msum = 0.f, ss = 0.f;
    for (int di = -1; di <= 1; ++di)
        for (int dj = -1; dj <= 1; ++dj) {
            int i = lh + di, j = lw + dj;
            if (i >= 0 && i < HS && j >= 0 && j < WS) {
                msum += mask[(b * H_ + 2 * i) * W_ + 2 * j];
                ss += ssq[(b << 12) + (i << 6) + j];
            }
        }
    maskedf[idx] = (msum == 0.0f) ? 1.0f : 0.0f;
    denom_inv[idx] = 1.0f / fmaxf(sqrtf(ss), 0.001f);
}

// ---------------- K0c: fused prep: im2col (bg,fg) + colsT, one launch ---------------------
__global__ void k_prep(const float* __restrict__ bgb, const float* __restrict__ fgb,
                       __hip_bfloat16* __restrict__ bhi, __hip_bfloat16* __restrict__ blo,
                       __hip_bfloat16* __restrict__ fhi, __hip_bfloat16* __restrict__ flo,
                       __hip_bfloat16* __restrict__ colsT) {
    int idx = blockIdx.x * 256 + threadIdx.x;
    if (idx < 2 * L_ * K1_) {  // im2col part (block-uniform split)
        int which = idx >= L_ * K1_;
        int id = which ? idx - L_ * K1_ : idx;
        const float* src = which ? fgb : bgb;
        __hip_bfloat16* hi = which ? fhi : bhi;
        __hip_bfloat16* lo = which ? flo : blo;
        int k = id % K1_;
        int l = id / K1_;
        int c = k / 9, r = k - 9 * c;
        int r3 = r / 3;
        int di = r3 - 1, dj = r - 3 * r3 - 1;
        int i = (l >> 6) + di, j = (l & 63) + dj;
        float v = 0.f;
        if (i >= 0 && i < HS && j >= 0 && j < WS) v = src[(c * H_ + 2 * i) * W_ + 2 * j];
        __hip_bfloat16 h = __float2bfloat16(v);
        hi[id] = h;
        lo[id] = __float2bfloat16(v - __bfloat162float(h));
    } else {  // colsT part
        int id = idx - 2 * L_ * K1_;  // NCOL*L, l fastest
        int l = id & 4095, n = id >> 12;
        int kj = n & 3, ki = (n >> 2) & 3, c = n >> 4;
        int y = 2 * (l >> 6) + ki - 1, x = 2 * (l & 63) + kj - 1;
        float v = 0.f;
        if (y >= 0 && y < H_ && x >= 0 && x < W_) v = bgb[(c * H_ + y) * W_ + x];
        colsT[id] = __float2bfloat16(v);
    }
}

// ---------------- K1: scores GEMM + fused diag-3 pass1 epilogue ---------------------------
// Writes Y interior (126x126 of its tile) directly via an LDS round-trip; writes raw
// scores only on 4-row/4-col strips (tile-boundary halo) for k_pass1_edge.
__global__ __launch_bounds__(256) void k_gemm1_mfma(const __hip_bfloat16* __restrict__ Ahi,
                                                    const __hip_bfloat16* __restrict__ Alo,
                                                    const __hip_bfloat16* __restrict__ Bhi,
                                                    const __hip_bfloat16* __restrict__ Blo,
                                                    const float* __restrict__ dinv,
                                                    float* __restrict__ scores,
                                                    float* __restrict__ Y) {
    __shared__ __align__(16) char shraw[65 * 129 * 4];  // union: staging (32KB) / epi tile (33.5KB)
    __hip_bfloat16* AsH = (__hip_bfloat16*)shraw;
    __hip_bfloat16* AsL = AsH + 4096;
    __hip_bfloat16* BsH = AsH + 8192;
    __hip_bfloat16* BsL = AsH + 12288;
    int t = threadIdx.x, lane = t & 63, w = t >> 6;
    int wm = w & 1, wn = w >> 1;
    int M0 = blockIdx.y * 128, N0 = blockIdx.x * 128;
    int srow = lane >> 2, schunk = (lane & 3) * 8;
    f32x4 acc[4][4] = {};
    for (int k0 = 0; k0 < K1_; k0 += 32) {
#pragma unroll
        for (int q = 0; q < 2; ++q) {
            int r = q * 64 + w * 16;
            int row = r + srow;
            size_t ga = (size_t)(M0 + row) * K1_ + k0 + schunk;
            size_t gb = (size_t)(N0 + row) * K1_ + k0 + schunk;
            int lo_ = r * 32;
            async_copy16(Ahi + ga, &AsH[lo_]);
            async_copy16(Alo + ga, &AsL[lo_]);
            async_copy16(Bhi + gb, &BsH[lo_]);
            async_copy16(Blo + gb, &BsL[lo_]);
        }
        __syncthreads();
        int q8 = (lane >> 4) * 8, mr = lane & 15;
        bf16x8 ah[4], al[4], bh[4], bl[4];
#pragma unroll
        for (int i = 0; i < 4; ++i) {
            int ra = (wm * 64 + i * 16 + mr) * 32 + q8;
            int rb = (wn * 64 + i * 16 + mr) * 32 + q8;
            ah[i] = *(const bf16x8*)&AsH[ra];
            al[i] = *(const bf16x8*)&AsL[ra];
            bh[i] = *(const bf16x8*)&BsH[rb];
            bl[i] = *(const bf16x8*)&BsL[rb];
        }
#pragma unroll
        for (int mt = 0; mt < 4; ++mt)
#pragma unroll
            for (int nt = 0; nt < 4; ++nt) {
                acc[mt][nt] = __builtin_amdgcn_mfma_f32_16x16x32_bf16(ah[mt], bh[nt], acc[mt][nt], 0, 0, 0);
                acc[mt][nt] = __builtin_amdgcn_mfma_f32_16x16x32_bf16(ah[mt], bl[nt], acc[mt][nt], 0, 0, 0);
                acc[mt][nt] = __builtin_amdgcn_mfma_f32_16x16x32_bf16(al[mt], bh[nt], acc[mt][nt], 0, 0, 0);
            }
        __syncthreads();
    }
    int col = lane & 15, rq = (lane >> 4) * 4;
    // strip writes: raw scores on rows/cols {0,1,126,127} of this tile
#pragma unroll
    for (int mt = 0; mt < 4; ++mt)
#pragma unroll
        for (int r = 0; r < 4; ++r) {
            int ml = wm * 64 + mt * 16 + rq + r;
            bool rstrip = (ml <= 1) || (ml >= 126);
            float dv = dinv[M0 + ml];
#pragma unroll
            for (int nt = 0; nt < 4; ++nt) {
                int nl = wn * 64 + nt * 16 + col;
                bool cstrip = (nl <= 1) || (nl >= 126);
                if (rstrip || cstrip)
                    scores[((size_t)(M0 + ml) << 12) + N0 + nl] = acc[mt][nt][r] * dv;
            }
        }
    // Y interior via two LDS half-tiles (rows 0..64, then 63..127)
    float* sm = (float*)shraw;
#pragma unroll
    for (int pass = 0; pass < 2; ++pass) {
        int lo = pass * 63;
        __syncthreads();  // prior pass reads / staging reads done
#pragma unroll
        for (int mt = 0; mt < 4; ++mt)
#pragma unroll
            for (int r = 0; r < 4; ++r) {
                int ml = wm * 64 + mt * 16 + rq + r;
                if (ml >= lo && ml <= lo + 64) {
                    float dv = dinv[M0 + ml];
#pragma unroll
                    for (int nt = 0; nt < 4; ++nt) {
                        int nl = wn * 64 + nt * 16 + col;
                        sm[(ml - lo) * 129 + nl] = acc[mt][nt][r] * dv;
                    }
                }
            }
        __syncthreads();
        int r0 = pass == 0 ? 1 : 64;
        for (int e = t; e < 63 * 126; e += 256) {
            int rr = r0 + e / 126;
            int cc = 1 + e % 126;
            int li = rr - lo;
            float y = sm[(li - 1) * 129 + cc - 1] + sm[li * 129 + cc] + sm[(li + 1) * 129 + cc + 1];
            Y[((size_t)(M0 + rr) << 12) + N0 + cc] = y;
        }
    }
}

// ---------------- K2a: Y boundary rows/cols from score strips (exact flat bounds) ---------
__global__ void k_pass1_edge(const float* __restrict__ scores, float* __restrict__ Y) {
    int idx = blockIdx.x * 256 + threadIdx.x;  // 2*64*4096
    int a, c;
    if (idx < 262144) {
        int ri = idx >> 12;  // 0..63
        a = (ri >> 1) * 128 + ((ri & 1) ? 127 : 0);
        c = idx & 4095;
    } else {
        int j = idx - 262144;
        int ci = j >> 12;
        c = (ci >> 1) * 128 + ((ci & 1) ? 127 : 0);
        a = j & 4095;
    }
    float acc = 0.f;
#pragma unroll
    for (int d = -1; d <= 1; ++d) {
        int aa = a + d, cc = c + d;
        if ((unsigned)aa < 4096u && (unsigned)cc < 4096u)
            acc += scores[((size_t)aa << 12) + cc];
    }
    Y[((size_t)a << 12) + c] = acc;
}

// ---------------- K2b: pass2 — 3-tap (rows +-64) + local-max exp + transpose -> softT -----
__global__ __launch_bounds__(256) void k_soft3(const float* __restrict__ Y,
                                               const float* __restrict__ maskedf,
                                               __hip_bfloat16* __restrict__ softT,
                                               float* __restrict__ pml, float* __restrict__ pz) {
    __shared__ float tile[64][65];
    __shared__ float red[16][64];
    __shared__ float mloc[64];
    int t = threadIdx.x;
    int sx4 = t & 15, lg = t >> 4;
    int bx = blockIdx.x, by = blockIdx.y;
    int s0 = bx * 64, l0 = by * 64;
    bool interior = (bx >= 1) && (bx <= 62) && (by >= 1) && (by <= 62);
    float p0 = -3.0e38f, p1 = -3.0e38f, p2 = -3.0e38f, p3 = -3.0e38f;
    if (interior) {
#pragma unroll
        for (int j = 0; j < 4; ++j) {
            int lloc = lg + 16 * j;
            int l = l0 + lloc;
            float a0 = 0.f, a1 = 0.f, a2 = 0.f, a3 = 0.f;
#pragma unroll
            for (int d2 = -1; d2 <= 1; ++d2) {
                const float* p = Y + ((size_t)(64 * (by + d2) + lloc) << 12) + 64 * (bx + d2) + 4 * sx4;
                float4 v = *(const float4*)p;
                a0 += v.x; a1 += v.y; a2 += v.z; a3 += v.w;
            }
            if (maskedf[l] != 0.f) { a0 = -1000.f; a1 = -1000.f; a2 = -1000.f; a3 = -1000.f; }
            tile[lloc][4 * sx4 + 0] = a0;
            tile[lloc][4 * sx4 + 1] = a1;
            tile[lloc][4 * sx4 + 2] = a2;
            tile[lloc][4 * sx4 + 3] = a3;
            p0 = fmaxf(p0, a0); p1 = fmaxf(p1, a1); p2 = fmaxf(p2, a2); p3 = fmaxf(p3, a3);
        }
    } else {
#pragma unroll
        for (int j = 0; j < 4; ++j) {
            int lloc = lg + 16 * j;
            int l = l0 + lloc;
            bool mk = (maskedf[l] != 0.f);
            float a0 = mk ? -1000.f : diag3Y(Y, l, s0 + 4 * sx4 + 0);
            float a1 = mk ? -1000.f : diag3Y(Y, l, s0 + 4 * sx4 + 1);
            float a2 = mk ? -1000.f : diag3Y(Y, l, s0 + 4 * sx4 + 2);
            float a3 = mk ? -1000.f : diag3Y(Y, l, s0 + 4 * sx4 + 3);
            tile[lloc][4 * sx4 + 0] = a0;
            tile[lloc][4 * sx4 + 1] = a1;
            tile[lloc][4 * sx4 + 2] = a2;
            tile[lloc][4 * sx4 + 3] = a3;
            p0 = fmaxf(p0, a0); p1 = fmaxf(p1, a1); p2 = fmaxf(p2, a2); p3 = fmaxf(p3, a3);
        }
    }
    red[lg][4 * sx4 + 0] = p0;
    red[lg][4 * sx4 + 1] = p1;
    red[lg][4 * sx4 + 2] = p2;
    red[lg][4 * sx4 + 3] = p3;
    __syncthreads();
    if (t < 64) {
        float m = -3.0e38f;
#pragma unroll
        for (int g = 0; g < 16; ++g) m = fmaxf(m, red[g][t]);
        mloc[t] = m;
        pml[(by << 12) + s0 + t] = m;
    }
    __syncthreads();
    float m0 = mloc[4 * sx4 + 0], m1 = mloc[4 * sx4 + 1], m2 = mloc[4 * sx4 + 2], m3 = mloc[4 * sx4 + 3];
    float z0 = 0.f, z1 = 0.f, z2 = 0.f, z3 = 0.f;
#pragma unroll
    for (int j = 0; j < 4; ++j) {
        int lloc = lg + 16 * j;
        float e0 = __expf(SCALE_ * (tile[lloc][4 * sx4 + 0] - m0));
        float e1 = __expf(SCALE_ * (tile[lloc][4 * sx4 + 1] - m1));
        float e2 = __expf(SCALE_ * (tile[lloc][4 * sx4 + 2] - m2));
        float e3 = __expf(SCALE_ * (tile[lloc][4 * sx4 + 3] - m3));
        tile[lloc][4 * sx4 + 0] = e0;
        tile[lloc][4 * sx4 + 1] = e1;
        tile[lloc][4 * sx4 + 2] = e2;
        tile[lloc][4 * sx4 + 3] = e3;
        z0 += e0; z1 += e1; z2 += e2; z3 += e3;
    }
    red[lg][4 * sx4 + 0] = z0;
    red[lg][4 * sx4 + 1] = z1;
    red[lg][4 * sx4 + 2] = z2;
    red[lg][4 * sx4 + 3] = z3;
    __syncthreads();
    if (t < 64) {
        float zz = 0.f;
#pragma unroll
        for (int g = 0; g < 16; ++g) zz += red[g][t];
        pz[(by << 12) + s0 + t] = zz;
    }
    int sxx = t & 63, tg4 = t >> 6;
#pragma unroll
    for (int i = 0; i < 16; ++i) {
        int sloc = tg4 * 16 + i;
        softT[((size_t)(s0 + sloc) << 12) + l0 + sxx] = __float2bfloat16(tile[sxx][sloc]);
    }
}

// ---------------- K3: fused zfix+rescale: block per s-row --------------------------------
__global__ __launch_bounds__(256) void k_zr(const float* __restrict__ pml,
                                            const float* __restrict__ pz,
                                            __hip_bfloat16* __restrict__ softT) {
    __shared__ float facs[64];
    int t = threadIdx.x;
    int s = blockIdx.x;
    if (t < 64) {
        float pmv = pml[(t << 12) + s];
        float m = pmv;
#pragma unroll
        for (int off = 1; off < 64; off <<= 1) m = fmaxf(m, __shfl_xor(m, off));
        float fc = __expf(SCALE_ * (pmv - m));
        float g = pz[(t << 12) + s] * fc;
#pragma unroll
        for (int off = 1; off < 64; off <<= 1) g += __shfl_xor(g, off);
        facs[t] = fc * (1.0f / g);
    }
    __syncthreads();
    size_t rowbase = (size_t)s << 12;
#pragma unroll
    for (int p = 0; p < 2; ++p) {
        int chunk = t + p * 256;
        float f = facs[chunk >> 3];
        bf16x8 v = *(const bf16x8*)(softT + rowbase + chunk * 8);
        bf16x8 o;
#pragma unroll
        for (int k = 0; k < 8; ++k) {
            unsigned short us = (unsigned short)v[k];
            float x = __uint_as_float((unsigned)us << 16) * f;
            __hip_bfloat16 r = __float2bfloat16(x);
            o[k] = *reinterpret_cast<short*>(&r);
        }
        *(bf16x8*)(softT + rowbase + chunk * 8) = o;
    }
}

// ---------------- K6: deconv GEMM, split-K z=2, BK=64, XCD-swizzled block ids -------------
__global__ __launch_bounds__(256) void k_gemm2_mfma(const __hip_bfloat16* __restrict__ softT,
                                                    const __hip_bfloat16* __restrict__ colsT,
                                                    float* __restrict__ patchP) {
    __shared__ __hip_bfloat16 As[128 * 64], Bs[64 * 64];
    int t = threadIdx.x, lane = t & 63, w = t >> 6;
    int wm = w & 1, wn = w >> 1;
    int flat = blockIdx.x + (blockIdx.y << 4) + (blockIdx.z << 9);  // grid (16,32,2)
    int xp = (flat >> 3) & 15;
    int yp = (flat & 7) | (((flat >> 7) & 3) << 3);
    int zp = flat >> 9;
    int M0 = yp * 128, N0 = xp * 64;
    int kbase = zp * 2048;
    f32x4 acc[4][2] = {};
    for (int k0 = kbase; k0 < kbase + 2048; k0 += 64) {
#pragma unroll
        for (int rp = 0; rp < 4; ++rp) {
            int chunk = rp * 256 + t;
            int row = chunk >> 3, c8 = (chunk & 7) * 8;
            async_copy16(softT + ((size_t)(M0 + row) << 12) + k0 + c8, &As[chunk * 8]);
        }
#pragma unroll
        for (int rp = 0; rp < 2; ++rp) {
            int chunk = rp * 256 + t;
            int row = chunk >> 3, c8 = (chunk & 7) * 8;
            async_copy16(colsT + ((size_t)(N0 + row) << 12) + k0 + c8, &Bs[chunk * 8]);
        }
        __syncthreads();
        int qc = lane >> 4, mr = lane & 15;
#pragma unroll
        for (int kk = 0; kk < 2; ++kk) {
            bf16x8 af[4], bfr[2];
#pragma unroll
            for (int i = 0; i < 4; ++i) {
                int rowa = wm * 64 + i * 16 + mr;
                af[i] = *(const bf16x8*)&As[rowa * 64 + (kk * 4 + qc) * 8];
            }
#pragma unroll
            for (int j = 0; j < 2; ++j) {
                int rowb = wn * 32 + j * 16 + mr;
                bfr[j] = *(const bf16x8*)&Bs[rowb * 64 + (kk * 4 + qc) * 8];
            }
#pragma unroll
            for (int mt = 0; mt < 4; ++mt)
#pragma unroll
                for (int nt = 0; nt < 2; ++nt)
                    acc[mt][nt] = __builtin_amdgcn_mfma_f32_16x16x32_bf16(af[mt], bfr[nt], acc[mt][nt], 0, 0, 0);
        }
        __syncthreads();
    }
    float* P = patchP + ((size_t)zp << 22);
    int col = lane & 15, rq = (lane >> 4) * 4;
#pragma unroll
    for (int mt = 0; mt < 4; ++mt)
#pragma unroll
        for (int r = 0; r < 4; ++r) {
            int m = M0 + wm * 64 + mt * 16 + rq + r;
#pragma unroll
            for (int nt = 0; nt < 2; ++nt) {
                int n = N0 + wn * 32 + nt * 16 + col;
                P[(size_t)m * 1024 + n] = acc[mt][nt][r];
            }
        }
}

// ---------------- K7: overlap-add gather over both K-partials, single batch ---------------
__global__ void k_col2im(const float* __restrict__ patchP, float* __restrict__ outb) {
    int idx = blockIdx.x * 256 + threadIdx.x;  // C*H*W
    if (idx >= C_ * H_ * W_) return;
    int x = idx & 127, y = (idx >> 7) & 127, c = idx >> 14;
    const float* P0 = patchP;
    const float* P1 = patchP + (1u << 22);
    float acc = 0.f;
    int ki0 = (y + 1) & 1, kj0 = (x + 1) & 1;
#pragma unroll
    for (int ki = ki0; ki < 4; ki += 2) {
        int i = (y + 1 - ki) >> 1;
        if (i < 0 || i >= HS) continue;
#pragma unroll
        for (int kj = kj0; kj < 4; kj += 2) {
            int j = (x + 1 - kj) >> 1;
            if (j < 0 || j >= WS) continue;
            size_t off = ((size_t)(i * 64 + j) << 10) + c * 16 + ki * 4 + kj;
            acc += P0[off] + P1[off];
        }
    }
    outb[idx] = acc;
}

extern "C" void kernel_launch(void* const* d_in, const int* in_sizes, int n_in,
                              void* d_out, int out_size, void* d_ws, size_t ws_size,
                              hipStream_t stream) {
    (void)in_sizes; (void)n_in; (void)out_size; (void)ws_size;
    const float* fg = (const float*)d_in[0];
    const float* bg = (const float*)d_in[1];
    const float* mask = (const float*)d_in[2];
    float* out = (float*)d_out;

    // ---- workspace (float offsets), ~171 MiB envelope ----
    float* ws = (float*)d_ws;
    float* scores = ws;                                          // strip-only scores (aliased by patchP later)
    float* patchP = ws;                                          // 2 x 4,194,304 f
    float* Y = ws + 16777216;                                    // 16,777,216 f
    __hip_bfloat16* bgcol_hi = (__hip_bfloat16*)(ws + 33554432); // moved out of Y region (Y now written by gemm1)
    __hip_bfloat16* bgcol_lo = (__hip_bfloat16*)(ws + 34734080);
    __hip_bfloat16* fgcol_hi = (__hip_bfloat16*)(ws + 35913728);
    __hip_bfloat16* fgcol_lo = (__hip_bfloat16*)(ws + 37093376);
    __hip_bfloat16* softT = (__hip_bfloat16*)(ws + 38273024);    // 16,777,216 bf16 = 8,388,608 f
    __hip_bfloat16* colsT = (__hip_bfloat16*)(ws + 46661632);    // 4,194,304 bf16 = 2,097,152 f
    float* pml = ws + 48758784;        // 262,144
    float* pz = ws + 49020928;         // 262,144
    float* denom_inv = ws + 49283072;  // 8,192 (B*L)
    float* maskedf = ws + 49291264;    // 8,192
    float* ssq = ws + 49299456;        // 8,192

    k_sumsq<<<(B_ * HS * WS) / 256, 256, 0, stream>>>(bg, ssq);
    k_patch_stats<<<(B_ * L_) / 256, 256, 0, stream>>>(mask, ssq, denom_inv, maskedf);

    for (int b = 0; b < B_; ++b) {
        const float* bgb = bg + (size_t)b * C_ * H_ * W_;
        const float* fgb = fg + (size_t)b * C_ * H_ * W_;

        k_prep<<<(2 * L_ * K1_ + NCOL * L_) / 256, 256, 0, stream>>>(bgb, fgb, bgcol_hi, bgcol_lo,
                                                                     fgcol_hi, fgcol_lo, colsT);

        dim3 g1(32, 32);
        k_gemm1_mfma<<<g1, 256, 0, stream>>>(bgcol_hi, bgcol_lo, fgcol_hi, fgcol_lo,
                                             denom_inv + b * L_, scores, Y);
        k_pass1_edge<<<2048, 256, 0, stream>>>(scores, Y);

        dim3 g4(64, 64);
        k_soft3<<<g4, 256, 0, stream>>>(Y, maskedf + b * L_, softT, pml, pz);
        k_zr<<<4096, 256, 0, stream>>>(pml, pz, softT);

        dim3 g5(16, 32, 2);
        k_gemm2_mfma<<<g5, 256, 0, stream>>>(softT, colsT, patchP);
        k_col2im<<<(C_ * H_ * W_) / 256, 256, 0, stream>>>(patchP, out + (size_t)b * C_ * H_ * W_);
    }
}

// Round 14
// 528.154 us; speedup vs baseline: 1.1978x; 1.0963x over previous
//
#include <hip/hip_runtime.h>
#include <hip/hip_bf16.h>

#define B_ 2
#define C_ 64
#define H_ 128
#define W_ 128
#define HS 64
#define WS 64
#define L_ 4096
#define S_ 4096
#define K1_ 576    // C*3*3
#define NCOL 1024  // C*4*4
#define SCALE_ 10.0f

typedef __attribute__((ext_vector_type(8))) short bf16x8;
typedef __attribute__((ext_vector_type(8))) _Float16 f16x8;
typedef __attribute__((ext_vector_type(4))) float f32x4;

// async global->LDS, 16B per lane (wave-uniform LDS base + lane*16).
__device__ __forceinline__ void async_copy16(const void* gsrc, void* ldst) {
    __builtin_amdgcn_global_load_lds(
        (__attribute__((address_space(1))) const void*)gsrc,
        (__attribute__((address_space(3))) void*)ldst, 16, 0, 0);
}

// transposed flat index within a 64x64 grid
__device__ __forceinline__ int TT(int x) { return ((x & 63) << 6) | (x >> 6); }

// generic 3-tap (d2) gather over Y with exact TT boundary semantics
__device__ __forceinline__ float diag3Y(const float* __restrict__ Y, int l, int s) {
    int tl = TT(l), ts = TT(s);
    float acc = 0.f;
#pragma unroll
    for (int d2 = -1; d2 <= 1; ++d2) {
        int p = tl + d2, q = ts + d2;
        if ((unsigned)p < 4096u && (unsigned)q < 4096u)
            acc += Y[((size_t)TT(p) << 12) + TT(q)];
    }
    return acc;
}

// ---------------- K0a: per-pixel channel sum-of-squares of downsampled bg ----------------
__global__ void k_sumsq(const float* __restrict__ bg, float* __restrict__ ssq) {
    int idx = blockIdx.x * 256 + threadIdx.x;  // B*64*64
    if (idx >= B_ * HS * WS) return;
    int pix = idx & 4095, b = idx >> 12;
    int i = pix >> 6, j = pix & 63;
    float ss = 0.f;
    for (int c = 0; c < C_; ++c) {
        float v = bg[((b * C_ + c) * H_ + 2 * i) * W_ + 2 * j];
        ss += v * v;
    }
    ssq[idx] = ss;
}

// ---------------- K0b: per-patch mask flag + 1/denom (3x3 box) ----------------
__global__ void k_patch_stats(const float* __restrict__ mask, const float* __restrict__ ssq,
                              float* __restrict__ denom_inv, float* __restrict__ maskedf) {
    int idx = blockIdx.x * 256 + threadIdx.x;  // B*L
    if (idx >= B_ * L_) return;
    int b = idx >> 12, l = idx & 4095, lh = l >> 6, lw = l & 63;
    float msum = 0.f, ss = 0.f;
    for (int di = -1; di <= 1; ++di)
        for (int dj = -1; dj <= 1; ++dj) {
            int i = lh + di, j = lw + dj;
            if (i >= 0 && i < HS && j >= 0 && j < WS) {
                msum += mask[(b * H_ + 2 * i) * W_ + 2 * j];
                ss += ssq[(b << 12) + (i << 6) + j];
            }
        }
    maskedf[idx] = (msum == 0.0f) ? 1.0f : 0.0f;
    denom_inv[idx] = 1.0f / fmaxf(sqrtf(ss), 0.001f);
}

// ---------------- K0c: fused prep: im2col (bg,fg -> fp16) + colsT (bf16), one launch ------
__global__ void k_prep(const float* __restrict__ bgb, const float* __restrict__ fgb,
                       _Float16* __restrict__ bcol, _Float16* __restrict__ fcol,
                       __hip_bfloat16* __restrict__ colsT) {
    int idx = blockIdx.x * 256 + threadIdx.x;
    if (idx < 2 * L_ * K1_) {  // im2col part (block-uniform split)
        int which = idx >= L_ * K1_;
        int id = which ? idx - L_ * K1_ : idx;
        const float* src = which ? fgb : bgb;
        _Float16* dst = which ? fcol : bcol;
        int k = id % K1_;
        int l = id / K1_;
        int c = k / 9, r = k - 9 * c;
        int r3 = r / 3;
        int di = r3 - 1, dj = r - 3 * r3 - 1;
        int i = (l >> 6) + di, j = (l & 63) + dj;
        float v = 0.f;
        if (i >= 0 && i < HS && j >= 0 && j < WS) v = src[(c * H_ + 2 * i) * W_ + 2 * j];
        dst[id] = (_Float16)v;
    } else {  // colsT part
        int id = idx - 2 * L_ * K1_;  // NCOL*L, l fastest
        int l = id & 4095, n = id >> 12;
        int kj = n & 3, ki = (n >> 2) & 3, c = n >> 4;
        int y = 2 * (l >> 6) + ki - 1, x = 2 * (l & 63) + kj - 1;
        float v = 0.f;
        if (y >= 0 && y < H_ && x >= 0 && x < W_) v = bgb[(c * H_ + y) * W_ + x];
        colsT[id] = __float2bfloat16(v);
    }
}

// ---------------- K1: scores GEMM (fp16 inputs, BK=64) + fused diag-3 pass1 epilogue ------
// fp16 (eps 2^-11) vs bf16 (2^-8): round-12's measured 0.957 absmax scales to ~0.12 < 0.33.
__global__ __launch_bounds__(256) void k_gemm1_mfma(const _Float16* __restrict__ A,
                                                    const _Float16* __restrict__ Bm,
                                                    const float* __restrict__ dinv,
                                                    float* __restrict__ scores,
                                                    float* __restrict__ Y) {
    __shared__ __align__(16) char shraw[65 * 129 * 4];  // union: staging 32KB / epi tile 33.5KB
    _Float16* As = (_Float16*)shraw;                    // 128 x 64 f16
    _Float16* Bs = As + 8192;                           // 128 x 64 f16
    int t = threadIdx.x, lane = t & 63, w = t >> 6;
    int wm = w & 1, wn = w >> 1;
    int M0 = blockIdx.y * 128, N0 = blockIdx.x * 128;
    f32x4 acc[4][4] = {};
    for (int k0 = 0; k0 < K1_; k0 += 64) {
#pragma unroll
        for (int rp = 0; rp < 4; ++rp) {
            int chunk = rp * 256 + t;  // 1024 chunks of 16B
            int row = chunk >> 3, c8 = (chunk & 7) * 8;
            async_copy16(A + (size_t)(M0 + row) * K1_ + k0 + c8, &As[chunk * 8]);
        }
#pragma unroll
        for (int rp = 0; rp < 4; ++rp) {
            int chunk = rp * 256 + t;
            int row = chunk >> 3, c8 = (chunk & 7) * 8;
            async_copy16(Bm + (size_t)(N0 + row) * K1_ + k0 + c8, &Bs[chunk * 8]);
        }
        __syncthreads();
        int qc = lane >> 4, mr = lane & 15;
#pragma unroll
        for (int kk = 0; kk < 2; ++kk) {
            f16x8 af[4], bfr[4];
#pragma unroll
            for (int i = 0; i < 4; ++i) {
                af[i] = *(const f16x8*)&As[(wm * 64 + i * 16 + mr) * 64 + (kk * 4 + qc) * 8];
                bfr[i] = *(const f16x8*)&Bs[(wn * 64 + i * 16 + mr) * 64 + (kk * 4 + qc) * 8];
            }
#pragma unroll
            for (int mt = 0; mt < 4; ++mt)
#pragma unroll
                for (int nt = 0; nt < 4; ++nt)
                    acc[mt][nt] = __builtin_amdgcn_mfma_f32_16x16x32_f16(af[mt], bfr[nt], acc[mt][nt], 0, 0, 0);
        }
        __syncthreads();
    }
    int col = lane & 15, rq = (lane >> 4) * 4;
    // strip writes: raw scores on rows/cols {0,1,126,127} of this tile
#pragma unroll
    for (int mt = 0; mt < 4; ++mt)
#pragma unroll
        for (int r = 0; r < 4; ++r) {
            int ml = wm * 64 + mt * 16 + rq + r;
            bool rstrip = (ml <= 1) || (ml >= 126);
            float dv = dinv[M0 + ml];
#pragma unroll
            for (int nt = 0; nt < 4; ++nt) {
                int nl = wn * 64 + nt * 16 + col;
                bool cstrip = (nl <= 1) || (nl >= 126);
                if (rstrip || cstrip)
                    scores[((size_t)(M0 + ml) << 12) + N0 + nl] = acc[mt][nt][r] * dv;
            }
        }
    // Y interior via two LDS half-tiles (rows 0..64, then 63..127); pow-2 indexing
    float* sm = (float*)shraw;
#pragma unroll
    for (int pass = 0; pass < 2; ++pass) {
        int lo = pass * 63;
        __syncthreads();
#pragma unroll
        for (int mt = 0; mt < 4; ++mt)
#pragma unroll
            for (int r = 0; r < 4; ++r) {
                int ml = wm * 64 + mt * 16 + rq + r;
                if (ml >= lo && ml <= lo + 64) {
                    float dv = dinv[M0 + ml];
#pragma unroll
                    for (int nt = 0; nt < 4; ++nt) {
                        int nl = wn * 64 + nt * 16 + col;
                        sm[(ml - lo) * 129 + nl] = acc[mt][nt][r] * dv;
                    }
                }
            }
        __syncthreads();
        int r0 = pass == 0 ? 1 : 64;
        for (int e = t; e < 63 * 128; e += 256) {
            int rr = r0 + (e >> 7);
            int cc = e & 127;
            if (cc < 1 || cc > 126) continue;
            int li = rr - lo;
            float y = sm[(li - 1) * 129 + cc - 1] + sm[li * 129 + cc] + sm[(li + 1) * 129 + cc + 1];
            Y[((size_t)(M0 + rr) << 12) + N0 + cc] = y;
        }
    }
}

// ---------------- K2a: Y boundary rows/cols from score strips (exact flat bounds) ---------
__global__ void k_pass1_edge(const float* __restrict__ scores, float* __restrict__ Y) {
    int idx = blockIdx.x * 256 + threadIdx.x;  // 2*64*4096
    int a, c;
    if (idx < 262144) {
        int ri = idx >> 12;  // 0..63
        a = (ri >> 1) * 128 + ((ri & 1) ? 127 : 0);
        c = idx & 4095;
    } else {
        int j = idx - 262144;
        int ci = j >> 12;
        c = (ci >> 1) * 128 + ((ci & 1) ? 127 : 0);
        a = j & 4095;
    }
    float acc = 0.f;
#pragma unroll
    for (int d = -1; d <= 1; ++d) {
        int aa = a + d, cc = c + d;
        if ((unsigned)aa < 4096u && (unsigned)cc < 4096u)
            acc += scores[((size_t)aa << 12) + cc];
    }
    Y[((size_t)a << 12) + c] = acc;
}

// ---------------- K2b: pass2 — 3-tap (rows +-64) + local-max exp + transpose -> softT -----
__global__ __launch_bounds__(256) void k_soft3(const float* __restrict__ Y,
                                               const float* __restrict__ maskedf,
                                               __hip_bfloat16* __restrict__ softT,
                                               float* __restrict__ pml, float* __restrict__ pz) {
    __shared__ float tile[64][65];
    __shared__ float red[16][64];
    __shared__ float mloc[64];
    int t = threadIdx.x;
    int sx4 = t & 15, lg = t >> 4;
    int bx = blockIdx.x, by = blockIdx.y;
    int s0 = bx * 64, l0 = by * 64;
    bool interior = (bx >= 1) && (bx <= 62) && (by >= 1) && (by <= 62);
    float p0 = -3.0e38f, p1 = -3.0e38f, p2 = -3.0e38f, p3 = -3.0e38f;
    if (interior) {
#pragma unroll
        for (int j = 0; j < 4; ++j) {
            int lloc = lg + 16 * j;
            int l = l0 + lloc;
            float a0 = 0.f, a1 = 0.f, a2 = 0.f, a3 = 0.f;
#pragma unroll
            for (int d2 = -1; d2 <= 1; ++d2) {
                const float* p = Y + ((size_t)(64 * (by + d2) + lloc) << 12) + 64 * (bx + d2) + 4 * sx4;
                float4 v = *(const float4*)p;
                a0 += v.x; a1 += v.y; a2 += v.z; a3 += v.w;
            }
            if (maskedf[l] != 0.f) { a0 = -1000.f; a1 = -1000.f; a2 = -1000.f; a3 = -1000.f; }
            tile[lloc][4 * sx4 + 0] = a0;
            tile[lloc][4 * sx4 + 1] = a1;
            tile[lloc][4 * sx4 + 2] = a2;
            tile[lloc][4 * sx4 + 3] = a3;
            p0 = fmaxf(p0, a0); p1 = fmaxf(p1, a1); p2 = fmaxf(p2, a2); p3 = fmaxf(p3, a3);
        }
    } else {
#pragma unroll
        for (int j = 0; j < 4; ++j) {
            int lloc = lg + 16 * j;
            int l = l0 + lloc;
            bool mk = (maskedf[l] != 0.f);
            float a0 = mk ? -1000.f : diag3Y(Y, l, s0 + 4 * sx4 + 0);
            float a1 = mk ? -1000.f : diag3Y(Y, l, s0 + 4 * sx4 + 1);
            float a2 = mk ? -1000.f : diag3Y(Y, l, s0 + 4 * sx4 + 2);
            float a3 = mk ? -1000.f : diag3Y(Y, l, s0 + 4 * sx4 + 3);
            tile[lloc][4 * sx4 + 0] = a0;
            tile[lloc][4 * sx4 + 1] = a1;
            tile[lloc][4 * sx4 + 2] = a2;
            tile[lloc][4 * sx4 + 3] = a3;
            p0 = fmaxf(p0, a0); p1 = fmaxf(p1, a1); p2 = fmaxf(p2, a2); p3 = fmaxf(p3, a3);
        }
    }
    red[lg][4 * sx4 + 0] = p0;
    red[lg][4 * sx4 + 1] = p1;
    red[lg][4 * sx4 + 2] = p2;
    red[lg][4 * sx4 + 3] = p3;
    __syncthreads();
    if (t < 64) {
        float m = -3.0e38f;
#pragma unroll
        for (int g = 0; g < 16; ++g) m = fmaxf(m, red[g][t]);
        mloc[t] = m;
        pml[(by << 12) + s0 + t] = m;
    }
    __syncthreads();
    float m0 = mloc[4 * sx4 + 0], m1 = mloc[4 * sx4 + 1], m2 = mloc[4 * sx4 + 2], m3 = mloc[4 * sx4 + 3];
    float z0 = 0.f, z1 = 0.f, z2 = 0.f, z3 = 0.f;
#pragma unroll
    for (int j = 0; j < 4; ++j) {
        int lloc = lg + 16 * j;
        float e0 = __expf(SCALE_ * (tile[lloc][4 * sx4 + 0] - m0));
        float e1 = __expf(SCALE_ * (tile[lloc][4 * sx4 + 1] - m1));
        float e2 = __expf(SCALE_ * (tile[lloc][4 * sx4 + 2] - m2));
        float e3 = __expf(SCALE_ * (tile[lloc][4 * sx4 + 3] - m3));
        tile[lloc][4 * sx4 + 0] = e0;
        tile[lloc][4 * sx4 + 1] = e1;
        tile[lloc][4 * sx4 + 2] = e2;
        tile[lloc][4 * sx4 + 3] = e3;
        z0 += e0; z1 += e1; z2 += e2; z3 += e3;
    }
    red[lg][4 * sx4 + 0] = z0;
    red[lg][4 * sx4 + 1] = z1;
    red[lg][4 * sx4 + 2] = z2;
    red[lg][4 * sx4 + 3] = z3;
    __syncthreads();
    if (t < 64) {
        float zz = 0.f;
#pragma unroll
        for (int g = 0; g < 16; ++g) zz += red[g][t];
        pz[(by << 12) + s0 + t] = zz;
    }
    int sxx = t & 63, tg4 = t >> 6;
#pragma unroll
    for (int i = 0; i < 16; ++i) {
        int sloc = tg4 * 16 + i;
        softT[((size_t)(s0 + sloc) << 12) + l0 + sxx] = __float2bfloat16(tile[sxx][sloc]);
    }
}

// ---------------- K3: fused zfix+rescale: block per s-row --------------------------------
__global__ __launch_bounds__(256) void k_zr(const float* __restrict__ pml,
                                            const float* __restrict__ pz,
                                            __hip_bfloat16* __restrict__ softT) {
    __shared__ float facs[64];
    int t = threadIdx.x;
    int s = blockIdx.x;
    if (t < 64) {
        float pmv = pml[(t << 12) + s];
        float m = pmv;
#pragma unroll
        for (int off = 1; off < 64; off <<= 1) m = fmaxf(m, __shfl_xor(m, off));
        float fc = __expf(SCALE_ * (pmv - m));
        float g = pz[(t << 12) + s] * fc;
#pragma unroll
        for (int off = 1; off < 64; off <<= 1) g += __shfl_xor(g, off);
        facs[t] = fc * (1.0f / g);
    }
    __syncthreads();
    size_t rowbase = (size_t)s << 12;
#pragma unroll
    for (int p = 0; p < 2; ++p) {
        int chunk = t + p * 256;
        float f = facs[chunk >> 3];
        bf16x8 v = *(const bf16x8*)(softT + rowbase + chunk * 8);
        bf16x8 o;
#pragma unroll
        for (int k = 0; k < 8; ++k) {
            unsigned short us = (unsigned short)v[k];
            float x = __uint_as_float((unsigned)us << 16) * f;
            __hip_bfloat16 r = __float2bfloat16(x);
            o[k] = *reinterpret_cast<short*>(&r);
        }
        *(bf16x8*)(softT + rowbase + chunk * 8) = o;
    }
}

// ---------------- K6: deconv GEMM, split-K z=2, BK=64, XCD-swizzled block ids -------------
__global__ __launch_bounds__(256) void k_gemm2_mfma(const __hip_bfloat16* __restrict__ softT,
                                                    const __hip_bfloat16* __restrict__ colsT,
                                                    float* __restrict__ patchP) {
    __shared__ __hip_bfloat16 As[128 * 64], Bs[64 * 64];
    int t = threadIdx.x, lane = t & 63, w = t >> 6;
    int wm = w & 1, wn = w >> 1;
    int flat = blockIdx.x + (blockIdx.y << 4) + (blockIdx.z << 9);  // grid (16,32,2)
    int xp = (flat >> 3) & 15;
    int yp = (flat & 7) | (((flat >> 7) & 3) << 3);
    int zp = flat >> 9;
    int M0 = yp * 128, N0 = xp * 64;
    int kbase = zp * 2048;
    f32x4 acc[4][2] = {};
    for (int k0 = kbase; k0 < kbase + 2048; k0 += 64) {
#pragma unroll
        for (int rp = 0; rp < 4; ++rp) {
            int chunk = rp * 256 + t;
            int row = chunk >> 3, c8 = (chunk & 7) * 8;
            async_copy16(softT + ((size_t)(M0 + row) << 12) + k0 + c8, &As[chunk * 8]);
        }
#pragma unroll
        for (int rp = 0; rp < 2; ++rp) {
            int chunk = rp * 256 + t;
            int row = chunk >> 3, c8 = (chunk & 7) * 8;
            async_copy16(colsT + ((size_t)(N0 + row) << 12) + k0 + c8, &Bs[chunk * 8]);
        }
        __syncthreads();
        int qc = lane >> 4, mr = lane & 15;
#pragma unroll
        for (int kk = 0; kk < 2; ++kk) {
            bf16x8 af[4], bfr[2];
#pragma unroll
            for (int i = 0; i < 4; ++i) {
                int rowa = wm * 64 + i * 16 + mr;
                af[i] = *(const bf16x8*)&As[rowa * 64 + (kk * 4 + qc) * 8];
            }
#pragma unroll
            for (int j = 0; j < 2; ++j) {
                int rowb = wn * 32 + j * 16 + mr;
                bfr[j] = *(const bf16x8*)&Bs[rowb * 64 + (kk * 4 + qc) * 8];
            }
#pragma unroll
            for (int mt = 0; mt < 4; ++mt)
#pragma unroll
                for (int nt = 0; nt < 2; ++nt)
                    acc[mt][nt] = __builtin_amdgcn_mfma_f32_16x16x32_bf16(af[mt], bfr[nt], acc[mt][nt], 0, 0, 0);
        }
        __syncthreads();
    }
    float* P = patchP + ((size_t)zp << 22);
    int col = lane & 15, rq = (lane >> 4) * 4;
#pragma unroll
    for (int mt = 0; mt < 4; ++mt)
#pragma unroll
        for (int r = 0; r < 4; ++r) {
            int m = M0 + wm * 64 + mt * 16 + rq + r;
#pragma unroll
            for (int nt = 0; nt < 2; ++nt) {
                int n = N0 + wn * 32 + nt * 16 + col;
                P[(size_t)m * 1024 + n] = acc[mt][nt][r];
            }
        }
}

// ---------------- K7: overlap-add gather over both K-partials, single batch ---------------
__global__ void k_col2im(const float* __restrict__ patchP, float* __restrict__ outb) {
    int idx = blockIdx.x * 256 + threadIdx.x;  // C*H*W
    if (idx >= C_ * H_ * W_) return;
    int x = idx & 127, y = (idx >> 7) & 127, c = idx >> 14;
    const float* P0 = patchP;
    const float* P1 = patchP + (1u << 22);
    float acc = 0.f;
    int ki0 = (y + 1) & 1, kj0 = (x + 1) & 1;
#pragma unroll
    for (int ki = ki0; ki < 4; ki += 2) {
        int i = (y + 1 - ki) >> 1;
        if (i < 0 || i >= HS) continue;
#pragma unroll
        for (int kj = kj0; kj < 4; kj += 2) {
            int j = (x + 1 - kj) >> 1;
            if (j < 0 || j >= WS) continue;
            size_t off = ((size_t)(i * 64 + j) << 10) + c * 16 + ki * 4 + kj;
            acc += P0[off] + P1[off];
        }
    }
    outb[idx] = acc;
}

extern "C" void kernel_launch(void* const* d_in, const int* in_sizes, int n_in,
                              void* d_out, int out_size, void* d_ws, size_t ws_size,
                              hipStream_t stream) {
    (void)in_sizes; (void)n_in; (void)out_size; (void)ws_size;
    const float* fg = (const float*)d_in[0];
    const float* bg = (const float*)d_in[1];
    const float* mask = (const float*)d_in[2];
    float* out = (float*)d_out;

    // ---- workspace (float offsets), ~190 MiB envelope ----
    float* ws = (float*)d_ws;
    float* scores = ws;                                          // strip-only scores
    float* patchP = ws;                                          // alias: 2 x 4,194,304 f
    float* Y = ws + 16777216;                                    // 16,777,216 f
    _Float16* bgcol = (_Float16*)(ws + 33554432);                // 2,359,296 f16
    _Float16* fgcol = (_Float16*)(ws + 34734080);
    __hip_bfloat16* softT = (__hip_bfloat16*)(ws + 38273024);    // 16,777,216 bf16
    __hip_bfloat16* colsT = (__hip_bfloat16*)(ws + 46661632);    // 4,194,304 bf16
    float* pml = ws + 48758784;        // 262,144
    float* pz = ws + 49020928;         // 262,144
    float* denom_inv = ws + 49283072;  // 8,192 (B*L)
    float* maskedf = ws + 49291264;    // 8,192
    float* ssq = ws + 49299456;        // 8,192

    k_sumsq<<<(B_ * HS * WS) / 256, 256, 0, stream>>>(bg, ssq);
    k_patch_stats<<<(B_ * L_) / 256, 256, 0, stream>>>(mask, ssq, denom_inv, maskedf);

    for (int b = 0; b < B_; ++b) {
        const float* bgb = bg + (size_t)b * C_ * H_ * W_;
        const float* fgb = fg + (size_t)b * C_ * H_ * W_;

        k_prep<<<(2 * L_ * K1_ + NCOL * L_) / 256, 256, 0, stream>>>(bgb, fgb, bgcol, fgcol, colsT);

        dim3 g1(32, 32);
        k_gemm1_mfma<<<g1, 256, 0, stream>>>(bgcol, fgcol, denom_inv + b * L_, scores, Y);
        k_pass1_edge<<<2048, 256, 0, stream>>>(scores, Y);

        dim3 g4(64, 64);
        k_soft3<<<g4, 256, 0, stream>>>(Y, maskedf + b * L_, softT, pml, pz);
        k_zr<<<4096, 256, 0, stream>>>(pml, pz, softT);

        dim3 g5(16, 32, 2);
        k_gemm2_mfma<<<g5, 256, 0, stream>>>(softT, colsT, patchP);
        k_col2im<<<(C_ * H_ * W_) / 256, 256, 0, stream>>>(patchP, out + (size_t)b * C_ * H_ * W_);
    }
}

// Round 15
// 489.582 us; speedup vs baseline: 1.2922x; 1.0788x over previous
//
#include <hip/hip_runtime.h>
#include <hip/hip_bf16.h>

#define B_ 2
#define C_ 64
#define H_ 128
#define W_ 128
#define HS 64
#define WS 64
#define L_ 4096
#define S_ 4096
#define K1_ 576    // C*3*3
#define NCOL 1024  // C*4*4
#define SCALE_ 10.0f

typedef __attribute__((ext_vector_type(8))) short bf16x8;
typedef __attribute__((ext_vector_type(8))) _Float16 f16x8;
typedef __attribute__((ext_vector_type(4))) float f32x4;

// async global->LDS, 16B per lane (wave-uniform LDS base + lane*16).
__device__ __forceinline__ void async_copy16(const void* gsrc, void* ldst) {
    __builtin_amdgcn_global_load_lds(
        (__attribute__((address_space(1))) const void*)gsrc,
        (__attribute__((address_space(3))) void*)ldst, 16, 0, 0);
}

// transposed flat index within a 64x64 grid
__device__ __forceinline__ int TT(int x) { return ((x & 63) << 6) | (x >> 6); }

// generic 3-tap (d2) gather over Y with exact TT boundary semantics
__device__ __forceinline__ float diag3Y(const float* __restrict__ Y, int l, int s) {
    int tl = TT(l), ts = TT(s);
    float acc = 0.f;
#pragma unroll
    for (int d2 = -1; d2 <= 1; ++d2) {
        int p = tl + d2, q = ts + d2;
        if ((unsigned)p < 4096u && (unsigned)q < 4096u)
            acc += Y[((size_t)TT(p) << 12) + TT(q)];
    }
    return acc;
}

// ---------------- K0a: per-pixel channel sum-of-squares of downsampled bg ----------------
__global__ void k_sumsq(const float* __restrict__ bg, float* __restrict__ ssq) {
    int idx = blockIdx.x * 256 + threadIdx.x;  // B*64*64
    if (idx >= B_ * HS * WS) return;
    int pix = idx & 4095, b = idx >> 12;
    int i = pix >> 6, j = pix & 63;
    float ss = 0.f;
    for (int c = 0; c < C_; ++c) {
        float v = bg[((b * C_ + c) * H_ + 2 * i) * W_ + 2 * j];
        ss += v * v;
    }
    ssq[idx] = ss;
}

// ---------------- K0b: per-patch mask flag + 1/denom (3x3 box) ----------------
__global__ void k_patch_stats(const float* __restrict__ mask, const float* __restrict__ ssq,
                              float* __restrict__ denom_inv, float* __restrict__ maskedf) {
    int idx = blockIdx.x * 256 + threadIdx.x;  // B*L
    if (idx >= B_ * L_) return;
    int b = idx >> 12, l = idx & 4095, lh = l >> 6, lw = l & 63;
    float msum = 0.f, ss = 0.f;
    for (int di = -1; di <= 1; ++di)
        for (int dj = -1; dj <= 1; ++dj) {
            int i = lh + di, j = lw + dj;
            if (i >= 0 && i < HS && j >= 0 && j < WS) {
                msum += mask[(b * H_ + 2 * i) * W_ + 2 * j];
                ss += ssq[(b << 12) + (i << 6) + j];
            }
        }
    maskedf[idx] = (msum == 0.0f) ? 1.0f : 0.0f;
    denom_inv[idx] = 1.0f / fmaxf(sqrtf(ss), 0.001f);
}

// ---------------- K0c: fused prep: im2col (bg,fg -> fp16) + colsT (bf16), one launch ------
__global__ void k_prep(const float* __restrict__ bgb, const float* __restrict__ fgb,
                       _Float16* __restrict__ bcol, _Float16* __restrict__ fcol,
                       __hip_bfloat16* __restrict__ colsT) {
    int idx = blockIdx.x * 256 + threadIdx.x;
    if (idx < 2 * L_ * K1_) {  // im2col part (block-uniform split)
        int which = idx >= L_ * K1_;
        int id = which ? idx - L_ * K1_ : idx;
        const float* src = which ? fgb : bgb;
        _Float16* dst = which ? fcol : bcol;
        int k = id % K1_;
        int l = id / K1_;
        int c = k / 9, r = k - 9 * c;
        int r3 = r / 3;
        int di = r3 - 1, dj = r - 3 * r3 - 1;
        int i = (l >> 6) + di, j = (l & 63) + dj;
        float v = 0.f;
        if (i >= 0 && i < HS && j >= 0 && j < WS) v = src[(c * H_ + 2 * i) * W_ + 2 * j];
        dst[id] = (_Float16)v;
    } else {  // colsT part
        int id = idx - 2 * L_ * K1_;  // NCOL*L, l fastest
        int l = id & 4095, n = id >> 12;
        int kj = n & 3, ki = (n >> 2) & 3, c = n >> 4;
        int y = 2 * (l >> 6) + ki - 1, x = 2 * (l & 63) + kj - 1;
        float v = 0.f;
        if (y >= 0 && y < H_ && x >= 0 && x < W_) v = bgb[(c * H_ + y) * W_ + x];
        colsT[id] = __float2bfloat16(v);
    }
}

// ---------------- K1: scores GEMM (fp16, BK=64, XOR-8 LDS swizzle) + diag-3 epilogue ------
// LDS row stride 128B = 32 banks: unswizzled, all 16 mr-lanes of a fragment read start at
// the same bank (16-way conflict). Store row R chunk c at position c^(R&7): writer fetches
// permuted global chunk (same cache lines), reader sees 8 bank groups x 2 lanes = free.
__global__ __launch_bounds__(256) void k_gemm1_mfma(const _Float16* __restrict__ A,
                                                    const _Float16* __restrict__ Bm,
                                                    const float* __restrict__ dinv,
                                                    float* __restrict__ scores,
                                                    float* __restrict__ Y) {
    __shared__ __align__(16) char shraw[65 * 129 * 4];  // union: staging 32KB / epi tile 33.5KB
    _Float16* As = (_Float16*)shraw;                    // 128 x 64 f16, XOR-8 swizzled
    _Float16* Bs = As + 8192;                           // 128 x 64 f16, XOR-8 swizzled
    int t = threadIdx.x, lane = t & 63, w = t >> 6;
    int wm = w & 1, wn = w >> 1;
    int M0 = blockIdx.y * 128, N0 = blockIdx.x * 128;
    f32x4 acc[4][4] = {};
    for (int k0 = 0; k0 < K1_; k0 += 64) {
#pragma unroll
        for (int rp = 0; rp < 4; ++rp) {
            int chunk = rp * 256 + t;  // 1024 chunks of 16B
            int row = chunk >> 3;
            int kc = (chunk & 7) ^ (row & 7);  // permuted global chunk -> swizzled LDS store
            async_copy16(A + (size_t)(M0 + row) * K1_ + k0 + kc * 8, &As[chunk * 8]);
        }
#pragma unroll
        for (int rp = 0; rp < 4; ++rp) {
            int chunk = rp * 256 + t;
            int row = chunk >> 3;
            int kc = (chunk & 7) ^ (row & 7);
            async_copy16(Bm + (size_t)(N0 + row) * K1_ + k0 + kc * 8, &Bs[chunk * 8]);
        }
        __syncthreads();
        int qc = lane >> 4, mr = lane & 15;
#pragma unroll
        for (int kk = 0; kk < 2; ++kk) {
            int c = kk * 4 + qc;
            f16x8 af[4], bfr[4];
#pragma unroll
            for (int i = 0; i < 4; ++i) {
                int ra = wm * 64 + i * 16 + mr;
                int rb = wn * 64 + i * 16 + mr;
                af[i] = *(const f16x8*)&As[ra * 64 + (c ^ (ra & 7)) * 8];
                bfr[i] = *(const f16x8*)&Bs[rb * 64 + (c ^ (rb & 7)) * 8];
            }
#pragma unroll
            for (int mt = 0; mt < 4; ++mt)
#pragma unroll
                for (int nt = 0; nt < 4; ++nt)
                    acc[mt][nt] = __builtin_amdgcn_mfma_f32_16x16x32_f16(af[mt], bfr[nt], acc[mt][nt], 0, 0, 0);
        }
        __syncthreads();
    }
    int col = lane & 15, rq = (lane >> 4) * 4;
    // strip writes: raw scores on rows/cols {0,1,126,127} of this tile
#pragma unroll
    for (int mt = 0; mt < 4; ++mt)
#pragma unroll
        for (int r = 0; r < 4; ++r) {
            int ml = wm * 64 + mt * 16 + rq + r;
            bool rstrip = (ml <= 1) || (ml >= 126);
            float dv = dinv[M0 + ml];
#pragma unroll
            for (int nt = 0; nt < 4; ++nt) {
                int nl = wn * 64 + nt * 16 + col;
                bool cstrip = (nl <= 1) || (nl >= 126);
                if (rstrip || cstrip)
                    scores[((size_t)(M0 + ml) << 12) + N0 + nl] = acc[mt][nt][r] * dv;
            }
        }
    // Y interior via two LDS half-tiles (rows 0..64, then 63..127); pow-2 indexing
    float* sm = (float*)shraw;
#pragma unroll
    for (int pass = 0; pass < 2; ++pass) {
        int lo = pass * 63;
        __syncthreads();
#pragma unroll
        for (int mt = 0; mt < 4; ++mt)
#pragma unroll
            for (int r = 0; r < 4; ++r) {
                int ml = wm * 64 + mt * 16 + rq + r;
                if (ml >= lo && ml <= lo + 64) {
                    float dv = dinv[M0 + ml];
#pragma unroll
                    for (int nt = 0; nt < 4; ++nt) {
                        int nl = wn * 64 + nt * 16 + col;
                        sm[(ml - lo) * 129 + nl] = acc[mt][nt][r] * dv;
                    }
                }
            }
        __syncthreads();
        int r0 = pass == 0 ? 1 : 64;
        for (int e = t; e < 63 * 128; e += 256) {
            int rr = r0 + (e >> 7);
            int cc = e & 127;
            if (cc < 1 || cc > 126) continue;
            int li = rr - lo;
            float y = sm[(li - 1) * 129 + cc - 1] + sm[li * 129 + cc] + sm[(li + 1) * 129 + cc + 1];
            Y[((size_t)(M0 + rr) << 12) + N0 + cc] = y;
        }
    }
}

// ---------------- K2a: Y boundary rows/cols from score strips (exact flat bounds) ---------
__global__ void k_pass1_edge(const float* __restrict__ scores, float* __restrict__ Y) {
    int idx = blockIdx.x * 256 + threadIdx.x;  // 2*64*4096
    int a, c;
    if (idx < 262144) {
        int ri = idx >> 12;  // 0..63
        a = (ri >> 1) * 128 + ((ri & 1) ? 127 : 0);
        c = idx & 4095;
    } else {
        int j = idx - 262144;
        int ci = j >> 12;
        c = (ci >> 1) * 128 + ((ci & 1) ? 127 : 0);
        a = j & 4095;
    }
    float acc = 0.f;
#pragma unroll
    for (int d = -1; d <= 1; ++d) {
        int aa = a + d, cc = c + d;
        if ((unsigned)aa < 4096u && (unsigned)cc < 4096u)
            acc += scores[((size_t)aa << 12) + cc];
    }
    Y[((size_t)a << 12) + c] = acc;
}

// ---------------- K2b: pass2 — 3-tap (rows +-64) + local-max exp + transpose -> softT -----
__global__ __launch_bounds__(256) void k_soft3(const float* __restrict__ Y,
                                               const float* __restrict__ maskedf,
                                               __hip_bfloat16* __restrict__ softT,
                                               float* __restrict__ pml, float* __restrict__ pz) {
    __shared__ float tile[64][65];
    __shared__ float red[16][64];
    __shared__ float mloc[64];
    int t = threadIdx.x;
    int sx4 = t & 15, lg = t >> 4;
    int bx = blockIdx.x, by = blockIdx.y;
    int s0 = bx * 64, l0 = by * 64;
    bool interior = (bx >= 1) && (bx <= 62) && (by >= 1) && (by <= 62);
    float p0 = -3.0e38f, p1 = -3.0e38f, p2 = -3.0e38f, p3 = -3.0e38f;
    if (interior) {
#pragma unroll
        for (int j = 0; j < 4; ++j) {
            int lloc = lg + 16 * j;
            int l = l0 + lloc;
            float a0 = 0.f, a1 = 0.f, a2 = 0.f, a3 = 0.f;
#pragma unroll
            for (int d2 = -1; d2 <= 1; ++d2) {
                const float* p = Y + ((size_t)(64 * (by + d2) + lloc) << 12) + 64 * (bx + d2) + 4 * sx4;
                float4 v = *(const float4*)p;
                a0 += v.x; a1 += v.y; a2 += v.z; a3 += v.w;
            }
            if (maskedf[l] != 0.f) { a0 = -1000.f; a1 = -1000.f; a2 = -1000.f; a3 = -1000.f; }
            tile[lloc][4 * sx4 + 0] = a0;
            tile[lloc][4 * sx4 + 1] = a1;
            tile[lloc][4 * sx4 + 2] = a2;
            tile[lloc][4 * sx4 + 3] = a3;
            p0 = fmaxf(p0, a0); p1 = fmaxf(p1, a1); p2 = fmaxf(p2, a2); p3 = fmaxf(p3, a3);
        }
    } else {
#pragma unroll
        for (int j = 0; j < 4; ++j) {
            int lloc = lg + 16 * j;
            int l = l0 + lloc;
            bool mk = (maskedf[l] != 0.f);
            float a0 = mk ? -1000.f : diag3Y(Y, l, s0 + 4 * sx4 + 0);
            float a1 = mk ? -1000.f : diag3Y(Y, l, s0 + 4 * sx4 + 1);
            float a2 = mk ? -1000.f : diag3Y(Y, l, s0 + 4 * sx4 + 2);
            float a3 = mk ? -1000.f : diag3Y(Y, l, s0 + 4 * sx4 + 3);
            tile[lloc][4 * sx4 + 0] = a0;
            tile[lloc][4 * sx4 + 1] = a1;
            tile[lloc][4 * sx4 + 2] = a2;
            tile[lloc][4 * sx4 + 3] = a3;
            p0 = fmaxf(p0, a0); p1 = fmaxf(p1, a1); p2 = fmaxf(p2, a2); p3 = fmaxf(p3, a3);
        }
    }
    red[lg][4 * sx4 + 0] = p0;
    red[lg][4 * sx4 + 1] = p1;
    red[lg][4 * sx4 + 2] = p2;
    red[lg][4 * sx4 + 3] = p3;
    __syncthreads();
    if (t < 64) {
        float m = -3.0e38f;
#pragma unroll
        for (int g = 0; g < 16; ++g) m = fmaxf(m, red[g][t]);
        mloc[t] = m;
        pml[(by << 12) + s0 + t] = m;
    }
    __syncthreads();
    float m0 = mloc[4 * sx4 + 0], m1 = mloc[4 * sx4 + 1], m2 = mloc[4 * sx4 + 2], m3 = mloc[4 * sx4 + 3];
    float z0 = 0.f, z1 = 0.f, z2 = 0.f, z3 = 0.f;
#pragma unroll
    for (int j = 0; j < 4; ++j) {
        int lloc = lg + 16 * j;
        float e0 = __expf(SCALE_ * (tile[lloc][4 * sx4 + 0] - m0));
        float e1 = __expf(SCALE_ * (tile[lloc][4 * sx4 + 1] - m1));
        float e2 = __expf(SCALE_ * (tile[lloc][4 * sx4 + 2] - m2));
        float e3 = __expf(SCALE_ * (tile[lloc][4 * sx4 + 3] - m3));
        tile[lloc][4 * sx4 + 0] = e0;
        tile[lloc][4 * sx4 + 1] = e1;
        tile[lloc][4 * sx4 + 2] = e2;
        tile[lloc][4 * sx4 + 3] = e3;
        z0 += e0; z1 += e1; z2 += e2; z3 += e3;
    }
    red[lg][4 * sx4 + 0] = z0;
    red[lg][4 * sx4 + 1] = z1;
    red[lg][4 * sx4 + 2] = z2;
    red[lg][4 * sx4 + 3] = z3;
    __syncthreads();
    if (t < 64) {
        float zz = 0.f;
#pragma unroll
        for (int g = 0; g < 16; ++g) zz += red[g][t];
        pz[(by << 12) + s0 + t] = zz;
    }
    int sxx = t & 63, tg4 = t >> 6;
#pragma unroll
    for (int i = 0; i < 16; ++i) {
        int sloc = tg4 * 16 + i;
        softT[((size_t)(s0 + sloc) << 12) + l0 + sxx] = __float2bfloat16(tile[sxx][sloc]);
    }
}

// ---------------- K3: fused zfix+rescale: block per s-row --------------------------------
__global__ __launch_bounds__(256) void k_zr(const float* __restrict__ pml,
                                            const float* __restrict__ pz,
                                            __hip_bfloat16* __restrict__ softT) {
    __shared__ float facs[64];
    int t = threadIdx.x;
    int s = blockIdx.x;
    if (t < 64) {
        float pmv = pml[(t << 12) + s];
        float m = pmv;
#pragma unroll
        for (int off = 1; off < 64; off <<= 1) m = fmaxf(m, __shfl_xor(m, off));
        float fc = __expf(SCALE_ * (pmv - m));
        float g = pz[(t << 12) + s] * fc;
#pragma unroll
        for (int off = 1; off < 64; off <<= 1) g += __shfl_xor(g, off);
        facs[t] = fc * (1.0f / g);
    }
    __syncthreads();
    size_t rowbase = (size_t)s << 12;
#pragma unroll
    for (int p = 0; p < 2; ++p) {
        int chunk = t + p * 256;
        float f = facs[chunk >> 3];
        bf16x8 v = *(const bf16x8*)(softT + rowbase + chunk * 8);
        bf16x8 o;
#pragma unroll
        for (int k = 0; k < 8; ++k) {
            unsigned short us = (unsigned short)v[k];
            float x = __uint_as_float((unsigned)us << 16) * f;
            __hip_bfloat16 r = __float2bfloat16(x);
            o[k] = *reinterpret_cast<short*>(&r);
        }
        *(bf16x8*)(softT + rowbase + chunk * 8) = o;
    }
}

// ---------------- K6: deconv GEMM, split-K z=2, BK=64, XOR-8 LDS swizzle ------------------
__global__ __launch_bounds__(256) void k_gemm2_mfma(const __hip_bfloat16* __restrict__ softT,
                                                    const __hip_bfloat16* __restrict__ colsT,
                                                    float* __restrict__ patchP) {
    __shared__ __hip_bfloat16 As[128 * 64], Bs[64 * 64];
    int t = threadIdx.x, lane = t & 63, w = t >> 6;
    int wm = w & 1, wn = w >> 1;
    int flat = blockIdx.x + (blockIdx.y << 4) + (blockIdx.z << 9);  // grid (16,32,2)
    int xp = (flat >> 3) & 15;
    int yp = (flat & 7) | (((flat >> 7) & 3) << 3);
    int zp = flat >> 9;
    int M0 = yp * 128, N0 = xp * 64;
    int kbase = zp * 2048;
    f32x4 acc[4][2] = {};
    for (int k0 = kbase; k0 < kbase + 2048; k0 += 64) {
#pragma unroll
        for (int rp = 0; rp < 4; ++rp) {
            int chunk = rp * 256 + t;
            int row = chunk >> 3;
            int kc = (chunk & 7) ^ (row & 7);
            async_copy16(softT + ((size_t)(M0 + row) << 12) + k0 + kc * 8, &As[chunk * 8]);
        }
#pragma unroll
        for (int rp = 0; rp < 2; ++rp) {
            int chunk = rp * 256 + t;
            int row = chunk >> 3;
            int kc = (chunk & 7) ^ (row & 7);
            async_copy16(colsT + ((size_t)(N0 + row) << 12) + k0 + kc * 8, &Bs[chunk * 8]);
        }
        __syncthreads();
        int qc = lane >> 4, mr = lane & 15;
#pragma unroll
        for (int kk = 0; kk < 2; ++kk) {
            int c = kk * 4 + qc;
            bf16x8 af[4], bfr[2];
#pragma unroll
            for (int i = 0; i < 4; ++i) {
                int rowa = wm * 64 + i * 16 + mr;
                af[i] = *(const bf16x8*)&As[rowa * 64 + (c ^ (rowa & 7)) * 8];
            }
#pragma unroll
            for (int j = 0; j < 2; ++j) {
                int rowb = wn * 32 + j * 16 + mr;
                bfr[j] = *(const bf16x8*)&Bs[rowb * 64 + (c ^ (rowb & 7)) * 8];
            }
#pragma unroll
            for (int mt = 0; mt < 4; ++mt)
#pragma unroll
                for (int nt = 0; nt < 2; ++nt)
                    acc[mt][nt] = __builtin_amdgcn_mfma_f32_16x16x32_bf16(af[mt], bfr[nt], acc[mt][nt], 0, 0, 0);
        }
        __syncthreads();
    }
    float* P = patchP + ((size_t)zp << 22);
    int col = lane & 15, rq = (lane >> 4) * 4;
#pragma unroll
    for (int mt = 0; mt < 4; ++mt)
#pragma unroll
        for (int r = 0; r < 4; ++r) {
            int m = M0 + wm * 64 + mt * 16 + rq + r;
#pragma unroll
            for (int nt = 0; nt < 2; ++nt) {
                int n = N0 + wn * 32 + nt * 16 + col;
                P[(size_t)m * 1024 + n] = acc[mt][nt][r];
            }
        }
}

// ---------------- K7: overlap-add gather over both K-partials, single batch ---------------
__global__ void k_col2im(const float* __restrict__ patchP, float* __restrict__ outb) {
    int idx = blockIdx.x * 256 + threadIdx.x;  // C*H*W
    if (idx >= C_ * H_ * W_) return;
    int x = idx & 127, y = (idx >> 7) & 127, c = idx >> 14;
    const float* P0 = patchP;
    const float* P1 = patchP + (1u << 22);
    float acc = 0.f;
    int ki0 = (y + 1) & 1, kj0 = (x + 1) & 1;
#pragma unroll
    for (int ki = ki0; ki < 4; ki += 2) {
        int i = (y + 1 - ki) >> 1;
        if (i < 0 || i >= HS) continue;
#pragma unroll
        for (int kj = kj0; kj < 4; kj += 2) {
            int j = (x + 1 - kj) >> 1;
            if (j < 0 || j >= WS) continue;
            size_t off = ((size_t)(i * 64 + j) << 10) + c * 16 + ki * 4 + kj;
            acc += P0[off] + P1[off];
        }
    }
    outb[idx] = acc;
}

extern "C" void kernel_launch(void* const* d_in, const int* in_sizes, int n_in,
                              void* d_out, int out_size, void* d_ws, size_t ws_size,
                              hipStream_t stream) {
    (void)in_sizes; (void)n_in; (void)out_size; (void)ws_size;
    const float* fg = (const float*)d_in[0];
    const float* bg = (const float*)d_in[1];
    const float* mask = (const float*)d_in[2];
    float* out = (float*)d_out;

    // ---- workspace (float offsets), ~190 MiB envelope ----
    float* ws = (float*)d_ws;
    float* scores = ws;                                          // strip-only scores
    float* patchP = ws;                                          // alias: 2 x 4,194,304 f
    float* Y = ws + 16777216;                                    // 16,777,216 f
    _Float16* bgcol = (_Float16*)(ws + 33554432);                // 2,359,296 f16
    _Float16* fgcol = (_Float16*)(ws + 34734080);
    __hip_bfloat16* softT = (__hip_bfloat16*)(ws + 38273024);    // 16,777,216 bf16
    __hip_bfloat16* colsT = (__hip_bfloat16*)(ws + 46661632);    // 4,194,304 bf16
    float* pml = ws + 48758784;        // 262,144
    float* pz = ws + 49020928;         // 262,144
    float* denom_inv = ws + 49283072;  // 8,192 (B*L)
    float* maskedf = ws + 49291264;    // 8,192
    float* ssq = ws + 49299456;        // 8,192

    k_sumsq<<<(B_ * HS * WS) / 256, 256, 0, stream>>>(bg, ssq);
    k_patch_stats<<<(B_ * L_) / 256, 256, 0, stream>>>(mask, ssq, denom_inv, maskedf);

    for (int b = 0; b < B_; ++b) {
        const float* bgb = bg + (size_t)b * C_ * H_ * W_;
        const float* fgb = fg + (size_t)b * C_ * H_ * W_;

        k_prep<<<(2 * L_ * K1_ + NCOL * L_) / 256, 256, 0, stream>>>(bgb, fgb, bgcol, fgcol, colsT);

        dim3 g1(32, 32);
        k_gemm1_mfma<<<g1, 256, 0, stream>>>(bgcol, fgcol, denom_inv + b * L_, scores, Y);
        k_pass1_edge<<<2048, 256, 0, stream>>>(scores, Y);

        dim3 g4(64, 64);
        k_soft3<<<g4, 256, 0, stream>>>(Y, maskedf + b * L_, softT, pml, pz);
        k_zr<<<4096, 256, 0, stream>>>(pml, pz, softT);

        dim3 g5(16, 32, 2);
        k_gemm2_mfma<<<g5, 256, 0, stream>>>(softT, colsT, patchP);
        k_col2im<<<(C_ * H_ * W_) / 256, 256, 0, stream>>>(patchP, out + (size_t)b * C_ * H_ * W_);
    }
}